// Round 9
// baseline (11183.208 us; speedup 1.0000x reference)
//
#include <hip/hip_runtime.h>

#define BATCH 64
#define ATOMS 64
#define CIN 3
#define KS 8
#define H 224
#define W 224
#define OH 56
#define OW 56
#define NLAT (BATCH*ATOMS*OH*OW)   // 12,845,056
#define IMGSZ (OH*OW*ATOMS)        // 200,704 elems per image (channel-last)
#define LAM 0.1f
#define ETA 0.1f
// a-buffer: fp16, zero-padded halo, pre-swizzled: [img][R=0..57][C=0..57][64]
// element (R,C,n) at slot ((n>>3) ^ ((2R+C)&7))*8 + (n&7) within the 64.
#define AROW 58
#define AIMG (AROW*AROW*64)        // 215,296 ushorts per image
#define NBLK 896                   // persistent grid (<= 4 blocks/CU x 256 CU)

typedef __attribute__((ext_vector_type(8)))  __bf16    bf16x8;
typedef __attribute__((ext_vector_type(8)))  _Float16  f16x8;
typedef __attribute__((ext_vector_type(16))) float     floatx16;

union FragU { uint4 u; bf16x8 v; };
union FragH { uint4 u; f16x8 v; };
union HalfBits { _Float16 h; unsigned short s; };

__device__ __forceinline__ float softthr(float u) {
    float p = u - LAM;  p = p > 0.f ? p : 0.f;
    float q = -u - LAM; q = q > 0.f ? q : 0.f;
    return p - q;
}
__device__ __forceinline__ unsigned short f2bf(float f) {   // RNE
    union { float f; unsigned int u; } c; c.f = f;
    unsigned int r = c.u + 0x7fffu + ((c.u >> 16) & 1u);
    return (unsigned short)(r >> 16);
}
__device__ __forceinline__ float bf2f(unsigned short h) {
    union { unsigned int u; float f; } c; c.u = ((unsigned int)h) << 16;
    return c.f;
}
__device__ __forceinline__ unsigned short f2h(float f) {    // fp16 bits, RNE
    HalfBits hb; hb.h = (_Float16)f; return hb.s;
}
__device__ __forceinline__ float h2f(unsigned short s) {
    HalfBits hb; hb.s = s; return (float)hb.h;
}
// swizzled ushort offset of atom n at padded coords (R,C) within an image
__device__ __forceinline__ size_t a_off(int img, int R, int C, int n) {
    return (((size_t)img*AROW + R)*AROW + C)*64
         + ((((n >> 3) ^ ((2*R + C) & 7)) << 3) | (n & 7));
}

// Zero the halo border cells of BOTH a-buffers; zero barrier counters.
__global__ void init_abuf_kernel(unsigned short* __restrict__ A,
                                 int* __restrict__ bar) {
    int idx = blockIdx.x * 256 + threadIdx.x;   // 128 img-buf x 228 cells x 16 quads
    if (idx == 0) { bar[0] = 0; bar[1] = 0; }
    int ib = idx / 3648, r = idx % 3648;
    int cell = r >> 4, q = r & 15;
    int R, C;
    if      (cell < 58)  { R = 0;  C = cell; }
    else if (cell < 116) { R = 57; C = cell - 58; }
    else if (cell < 172) { R = cell - 116 + 1; C = 0; }
    else                 { R = cell - 172 + 1; C = 57; }
    size_t off = (size_t)ib*AIMG + ((size_t)R*AROW + C)*64 + q*4;
    *(ushort4*)(A + off) = make_ushort4(0, 0, 0, 0);
}

// DT[((c*8+y)*8+x)*64 + m] = D[m,c,y,x]
__global__ void prep_dt_kernel(const float* __restrict__ D,
                               float* __restrict__ DT) {
    int idx = blockIdx.x * 256 + threadIdx.x;
    if (idx < CIN*KS*KS*ATOMS) {
        int m = idx & 63;
        int r = idx >> 6;
        int xk = r & 7, y = (r >> 3) & 7, c = r >> 6;
        DT[idx] = D[((m*CIN + c)*KS + y)*KS + xk];
    }
}

// 9 table-sets (inclusion-exclusion for boundary classes), 9 dpq each.
__global__ void prep_gram_kernel(const float* __restrict__ DT,
                                 float* __restrict__ G) {
    int blk = blockIdx.x;              // td*16 + nchunk
    int td = blk >> 4;
    int tbl = td / 9, dpq = td % 9;
    int dp = dpq / 3, dq = dpq % 3;
    int di = 1 - dp, dj = 1 - dq;
    int ylo = (0 > -4*di) ? 0 : -4*di;
    int yhi = (8 < 8-4*di) ? 8 : 8-4*di;
    int xlo = (0 > -4*dj) ? 0 : -4*dj;
    int xhi = (8 < 8-4*dj) ? 8 : 8-4*dj;
    if (tbl==1 || tbl==5 || tbl==6) { if (yhi > 2) yhi = 2; }
    if (tbl==2 || tbl==7 || tbl==8) { if (ylo < 6) ylo = 6; }
    if (tbl==3 || tbl==5 || tbl==7) { if (xhi > 2) xhi = 2; }
    if (tbl==4 || tbl==6 || tbl==8) { if (xlo < 6) xlo = 6; }
    float sign = (tbl >= 1 && tbl <= 4) ? -1.f : 1.f;
    int t = threadIdx.x;
    int m = t & 63;
    int n = (blk & 15)*4 + (t >> 6);
    float s = 0.f;
    for (int c = 0; c < CIN; ++c)
        for (int y = ylo; y < yhi; ++y)
            for (int x = xlo; x < xhi; ++x)
                s += DT[((c*8+y)*8+x)*64 + m] *
                     DT[((c*8+y+4*di)*8 + (x+4*dj))*64 + n];
    G[td*4096 + n*64 + m] = sign * s;
}

// Pack G into MFMA A-operand layout, split FP16 hi/lo.
__global__ void prep_packg_kernel(const float* __restrict__ G,
                                  unsigned short* __restrict__ GAh,
                                  unsigned short* __restrict__ GAl) {
    int g = blockIdx.x * 256 + threadIdx.x;      // 162*256 = 41472 groups
    int lane = g & 63;
    int r = g >> 6;
    int kstep = r & 3; r >>= 2;
    int mhalf = r & 1; int td = r >> 1;          // tbl*9+dpq
    int m = mhalf*32 + (lane & 31);
    int n = kstep*16 + (lane >> 5)*8;
    const float* src = G + td*4096 + n*64 + m;
#pragma unroll
    for (int j = 0; j < 8; ++j) {
        float v = src[j*64];
        unsigned short h = f2h(v);
        GAh[g*8 + j] = h;
        GAl[g*8 + j] = f2h(v - h2f(h));
    }
}

// Pack D into MFMA A-layout for conv_b: K=192, k = c*64+y*8+x. (bf16 split)
__global__ void prep_packd_kernel(const float* __restrict__ D,
                                  unsigned short* __restrict__ DAh,
                                  unsigned short* __restrict__ DAl) {
    int g = blockIdx.x * 256 + threadIdx.x;
    if (g >= 1536) return;
    int lane = g & 63;
    int r = g >> 6;
    int kstep = r % 12, mhalf = r / 12;
    int m = mhalf*32 + (lane & 31);
    int k0 = kstep*16 + (lane >> 5)*8;
#pragma unroll
    for (int j = 0; j < 8; ++j) {
        float v = D[m*192 + k0 + j];
        unsigned short h = f2bf(v);
        DAh[g*8 + j] = h;
        DAl[g*8 + j] = f2bf(v - bf2f(h));
    }
}

// b = conv2d(x, D, stride4, pad2); u = 0.1*b; a1 = softthr(u) -> A0 (swizzled).
__global__ __launch_bounds__(256) void conv_b_kernel(
        const float* __restrict__ x,
        const unsigned short* __restrict__ DAh,
        const unsigned short* __restrict__ DAl,
        float* __restrict__ b, float* __restrict__ u,
        unsigned short* __restrict__ A0) {
    __shared__ __align__(16) unsigned short xth[CIN*36*36];
    __shared__ __align__(16) unsigned short xtl[CIN*36*36];
    __shared__ float ot[64*65];
    int blk = blockIdx.x;
    int img = blk / 49, tile = blk % 49;
    int i0 = (tile / 7) * 8, j0 = (tile % 7) * 8;
    int t = threadIdx.x;
    int r0 = 4*i0 - 2, c0 = 4*j0 - 2;
    for (int f = t; f < CIN*36*36; f += 256) {
        int cc = f / 1296, rem = f % 1296;
        int rr = rem / 36, qq = rem % 36;
        int Y = r0 + rr, X = c0 + qq;
        float v = 0.f;
        if (Y >= 0 && Y < H && X >= 0 && X < W)
            v = x[((img*CIN + cc)*H + Y)*W + X];
        unsigned short h = f2bf(v);
        xth[f] = h;
        xtl[f] = f2bf(v - bf2f(h));
    }
    __syncthreads();
    int lane = t & 63, wave = t >> 6;
    int mhalf = wave & 1, poshalf = wave >> 1;
    int pos = poshalf*32 + (lane & 31), pi = pos >> 3, pj = pos & 7;
    int khalf = lane >> 5;
    floatx16 acc;
#pragma unroll
    for (int i = 0; i < 16; ++i) acc[i] = 0.f;
    const uint4* Ah4 = (const uint4*)DAh;
    const uint4* Al4 = (const uint4*)DAl;
#pragma unroll 3
    for (int kstep = 0; kstep < 12; ++kstep) {
        int k0 = kstep*16 + khalf*8;
        int cc = k0 >> 6, yy = (k0 >> 3) & 7;
        int boff = cc*1296 + (4*pi + yy)*36 + 4*pj;
        FragU ah, al, bh, bl;
        ah.u = Ah4[(mhalf*12 + kstep)*64 + lane];
        al.u = Al4[(mhalf*12 + kstep)*64 + lane];
        const uint2* ph = (const uint2*)(xth + boff);
        uint2 h0 = ph[0], h1 = ph[1];
        bh.u = make_uint4(h0.x, h0.y, h1.x, h1.y);
        const uint2* pl = (const uint2*)(xtl + boff);
        uint2 l0 = pl[0], l1 = pl[1];
        bl.u = make_uint4(l0.x, l0.y, l1.x, l1.y);
        acc = __builtin_amdgcn_mfma_f32_32x32x16_bf16(ah.v, bh.v, acc, 0, 0, 0);
        acc = __builtin_amdgcn_mfma_f32_32x32x16_bf16(ah.v, bl.v, acc, 0, 0, 0);
        acc = __builtin_amdgcn_mfma_f32_32x32x16_bf16(al.v, bh.v, acc, 0, 0, 0);
    }
#pragma unroll
    for (int r16 = 0; r16 < 16; ++r16) {
        int row = (r16 & 3) + 8*(r16 >> 2) + 4*khalf;
        ot[(mhalf*32 + row)*65 + pos] = acc[r16];
    }
    __syncthreads();
    int m = t & 63;
    float* bp = b + (size_t)img*IMGSZ;
    float* up = u + (size_t)img*IMGSZ;
#pragma unroll
    for (int e = 0; e < 16; ++e) {
        int pp = e*4 + (t >> 6);
        int gi = i0 + (pp >> 3), gj = j0 + (pp & 7);
        int gidx = (gi*OW + gj)*64 + m;
        float v = ot[m*65 + pp];
        bp[gidx] = v;
        float uv = ETA * v;
        up[gidx] = uv;
        A0[a_off(img, gi + 1, gj + 1, m)] = f2h(softthr(uv));
    }
}

// ---- interior fast-path helpers: double-buffered register pipeline ----
__device__ __forceinline__ void load_a(uint4 (&A)[9], const uint4* __restrict__ Gh4,
                                       const uint4* __restrict__ Gl4,
                                       int txoff, int bb, int mhalf, int lane) {
    int dq = bb >> 2, ks = bb & 3;
#pragma unroll
    for (int dp = 0; dp < 3; ++dp) {
        int abase = (((3*dp + dq)*2 + mhalf)*4 + ks)*64 + lane;
        A[dp*3+0] = Gh4[abase];
        A[dp*3+1] = Gl4[abase];
        A[dp*3+2] = Gh4[txoff + abase];
    }
}
__device__ __forceinline__ void load_b(uint4 (&B)[4], const uint4* __restrict__ B4h,
                                       int bb, int khalf, int pjx, int sb4) {
    int dq = bb >> 2, ks = bb & 3;
    int kg2 = ks*2 + khalf;
#pragma unroll
    for (int p = 0; p < 4; ++p) {
        int rc = p*58 + pjx + dq;
        B[p] = B4h[rc*8 + (kg2 ^ ((rc + sb4) & 7))];
    }
}
__device__ __forceinline__ void do_mfma(floatx16& acc0, floatx16& acc1,
                                        const uint4 (&A)[9], const uint4 (&B)[4],
                                        unsigned msel) {
    __builtin_amdgcn_s_setprio(1);
#pragma unroll
    for (int dp = 0; dp < 3; ++dp) {
        FragH a0, a1, ax, b0, b1, bm0, bm1;
        a0.u = A[dp*3+0]; a1.u = A[dp*3+1]; ax.u = A[dp*3+2];
        b0.u = B[dp]; b1.u = B[dp+1];
        bm0.u = make_uint4(b0.u.x & msel, b0.u.y & msel,
                           b0.u.z & msel, b0.u.w & msel);
        bm1.u = make_uint4(b1.u.x & msel, b1.u.y & msel,
                           b1.u.z & msel, b1.u.w & msel);
        acc0 = __builtin_amdgcn_mfma_f32_32x32x16_f16(a0.v, b0.v, acc0, 0,0,0);
        acc1 = __builtin_amdgcn_mfma_f32_32x32x16_f16(a0.v, b1.v, acc1, 0,0,0);
        acc0 = __builtin_amdgcn_mfma_f32_32x32x16_f16(a1.v, b0.v, acc0, 0,0,0);
        acc1 = __builtin_amdgcn_mfma_f32_32x32x16_f16(a1.v, b1.v, acc1, 0,0,0);
        acc0 = __builtin_amdgcn_mfma_f32_32x32x16_f16(ax.v, bm0.v, acc0, 0,0,0);
        acc1 = __builtin_amdgcn_mfma_f32_32x32x16_f16(ax.v, bm1.v, acc1, 0,0,0);
    }
    __builtin_amdgcn_s_setprio(0);
}

// One LCA band step (R5/R6-verified numerics, unchanged).
__device__ __forceinline__ void band_step(
        int task, const float* __restrict__ b, float* __restrict__ u,
        const unsigned short* __restrict__ Ain,
        unsigned short* __restrict__ Aout,
        const unsigned short* __restrict__ GAh,
        const unsigned short* __restrict__ GAl,
        float* __restrict__ out, int last,
        unsigned char* smem) {
    unsigned short* at2h = (unsigned short*)smem;
    int img = task / 28, bandi = task % 28;
    int i0 = bandi*2;
    int t = threadIdx.x;
    __syncthreads();                 // LDS free from previous use
    {
        const char* gbase = (const char*)(Ain + (((size_t)img*AROW + i0)*AROW)*64)
                          + (t & 63)*16;
        char* lbase = (char*)smem;
        int w = t >> 6;
        for (int c = w; c < 29; c += 4) {
            __builtin_amdgcn_global_load_lds(
                (const __attribute__((address_space(1))) unsigned int*)(gbase + c*1024),
                (__attribute__((address_space(3))) unsigned int*)(lbase + c*1024),
                16, 0, 0);
        }
    }
    __syncthreads();
    int lane = t & 63, wave = t >> 6;
    int mhalf = wave & 1, cgrp = wave >> 1;
    int khalf = lane >> 5, cl = lane & 31;
    int pj = cgrp*32 + cl;
    int pjx = (pj < 56) ? pj : 0;
    int sb4 = (bandi & 1) << 2;
    floatx16 acc0, acc1;
#pragma unroll
    for (int i = 0; i < 16; ++i) { acc0[i] = 0.f; acc1[i] = 0.f; }
    const uint4* Gh4 = (const uint4*)GAh;
    const uint4* Gl4 = (const uint4*)GAl;
    const uint4* B4h = (const uint4*)at2h;
    int tbx = (cgrp == 0) ? 3 : 4;
    int txoff = (tbx*9)*512;
    unsigned msel = (cl == ((cgrp == 0) ? 0 : 23)) ? 0xFFFFFFFFu : 0u;
    bool edge = (bandi == 0) || (bandi == 27);
    if (!edge) {
        uint4 Aa[9], Ab[9], Ba[4], Bb[4];
        load_a(Aa, Gh4, Gl4, txoff, 0, mhalf, lane);
        load_b(Ba, B4h, 0, khalf, pjx, sb4);
#pragma unroll 1
        for (int it2 = 0; it2 < 6; ++it2) {
            int bb = it2*2;
            load_a(Ab, Gh4, Gl4, txoff, bb+1, mhalf, lane);
            load_b(Bb, B4h, bb+1, khalf, pjx, sb4);
            do_mfma(acc0, acc1, Aa, Ba, msel);
            if (it2 < 5) {
                load_a(Aa, Gh4, Gl4, txoff, bb+2, mhalf, lane);
                load_b(Ba, B4h, bb+2, khalf, pjx, sb4);
            }
            do_mfma(acc0, acc1, Ab, Bb, msel);
        }
    } else {
        int ymask, tby, tbc;
        if (bandi == 0) { ymask = 1; tby = 1; tbc = (cgrp == 0) ? 5 : 6; }
        else            { ymask = 2; tby = 2; tbc = (cgrp == 0) ? 7 : 8; }
#pragma unroll 1
        for (int dq = 0; dq < 3; ++dq) {
#pragma unroll 1
            for (int kstep = 0; kstep < 4; ++kstep) {
                int kg2 = kstep*2 + khalf;
#pragma unroll
                for (int dp = 0; dp < 3; ++dp) {
                    int rc0 = dp*58 + pjx + dq;
                    int rc1 = rc0 + 58;
                    FragH B0, B1;
                    B0.u = B4h[rc0*8 + (kg2 ^ ((rc0 + sb4) & 7))];
                    B1.u = B4h[rc1*8 + (kg2 ^ ((rc1 + sb4) & 7))];
                    for (int tm = 0; tm < 6; ++tm) {
                        int td = (tm < 2) ? 0 : (tm == 2) ? tbx : (tm < 5) ? tby : tbc;
                        const uint4* Ap = ((tm == 1) || (tm == 4)) ? Gl4 : Gh4;
                        bool masked = (tm == 2) || (tm == 5);
                        int am = (tm < 3) ? 3 : ymask;
                        FragH a;
                        a.u = Ap[(((td*9 + 3*dp + dq)*2 + mhalf)*4 + kstep)*64 + lane];
                        if (!masked) {
                            if (am & 1)
                                acc0 = __builtin_amdgcn_mfma_f32_32x32x16_f16(a.v, B0.v, acc0, 0,0,0);
                            if (am & 2)
                                acc1 = __builtin_amdgcn_mfma_f32_32x32x16_f16(a.v, B1.v, acc1, 0,0,0);
                        } else {
                            if (am & 1) {
                                FragH bm;
                                bm.u = make_uint4(B0.u.x & msel, B0.u.y & msel,
                                                  B0.u.z & msel, B0.u.w & msel);
                                acc0 = __builtin_amdgcn_mfma_f32_32x32x16_f16(a.v, bm.v, acc0, 0,0,0);
                            }
                            if (am & 2) {
                                FragH bm;
                                bm.u = make_uint4(B1.u.x & msel, B1.u.y & msel,
                                                  B1.u.z & msel, B1.u.w & msel);
                                acc1 = __builtin_amdgcn_mfma_f32_32x32x16_f16(a.v, bm.v, acc1, 0,0,0);
                            }
                        }
                    }
                }
            }
        }
    }
    __syncthreads();                   // at2 dead; overlay fp32 ot[pos][m]
    float* ot = (float*)smem;          // 112*65*4 = 29120 B
    if (pj < 56) {
#pragma unroll
        for (int r16 = 0; r16 < 16; ++r16) {
            int row = (r16 & 3) + 8*(r16 >> 2) + 4*khalf;
            int m = mhalf*32 + row;
            ot[pj*65 + m] = acc0[r16];
            ot[(56 + pj)*65 + m] = acc1[r16];
        }
    }
    __syncthreads();
    const float* bp = b + (size_t)img*IMGSZ;
    float* up = u + (size_t)img*IMGSZ;          // in-place state update
#pragma unroll 7
    for (int pass = 0; pass < 28; ++pass) {     // 2*56*64 elems, lane = n
        int idx = pass*256 + t;
        int n = idx & 63;
        int rest = idx >> 6;                    // 0..111
        int pi = (rest >= 56) ? 1 : 0;
        int j = rest - 56*pi;
        int g = ((i0 + pi)*OW + j)*64 + n;
        float uo = up[g];
        float gram = ot[(pi*56 + j)*65 + n];
        float un = uo + ETA * (bp[g] - uo - gram + softthr(uo));
        if (last) {
            out[(((size_t)img*ATOMS + n)*OH + (i0 + pi))*OW + j] = softthr(un);
        } else {
            up[g] = un;
            Aout[a_off(img, i0 + pi + 1, j + 1, n)] = f2h(softthr(un));
        }
    }
}

// Software grid barrier: device-scope atomics (agent scope lowers to the
// cross-XCD L2 writeback/invalidate on gfx950). Safe because all NBLK
// blocks are co-resident by capacity arithmetic (LDS 29696 -> 5/CU,
// VGPR<=128 -> 4/CU, 4x256=1024 >= 896).
__device__ __forceinline__ void grid_barrier(int* cnt, int* gen, int target) {
    __syncthreads();
    if (threadIdx.x == 0) {
        __threadfence();   // release prior writes (L2 writeback)
        int arrived = __hip_atomic_fetch_add(cnt, 1, __ATOMIC_ACQ_REL,
                                             __HIP_MEMORY_SCOPE_AGENT) + 1;
        if (arrived == NBLK) {
            __hip_atomic_store(cnt, 0, __ATOMIC_RELAXED, __HIP_MEMORY_SCOPE_AGENT);
            __hip_atomic_fetch_add(gen, 1, __ATOMIC_RELEASE,
                                   __HIP_MEMORY_SCOPE_AGENT);
        } else {
            while (__hip_atomic_load(gen, __ATOMIC_ACQUIRE,
                                     __HIP_MEMORY_SCOPE_AGENT) < target)
                __builtin_amdgcn_s_sleep(8);
        }
        __threadfence();   // acquire (L1/L2 invalidate)
    }
    __syncthreads();
}

// Persistent kernel: 9 LCA iterations, software grid barrier between them.
// 896 blocks x 256 thr; each block does 2 adjacent band-tasks per iteration.
__global__ __launch_bounds__(256, 4) void lca_persist(
        const float* b, float* u,
        unsigned short* A0, unsigned short* A1,
        const unsigned short* GAh, const unsigned short* GAl,
        float* out, int* bar) {
    __shared__ __align__(1024) unsigned char smem[29696];
    int blk = blockIdx.x;
    int* cnt = bar;
    int* gen = bar + 1;
#pragma unroll 1
    for (int it = 0; it < 9; ++it) {
        const unsigned short* Ain = (it & 1) ? A1 : A0;
        unsigned short* Aout      = (it & 1) ? A0 : A1;
        int last = (it == 8);
#pragma unroll 1
        for (int s = 0; s < 2; ++s) {
            band_step(blk*2 + s, b, u, Ain, Aout, GAh, GAl, out, last, smem);
        }
        if (!last) grid_barrier(cnt, gen, it + 1);
    }
}

extern "C" void kernel_launch(void* const* d_in, const int* in_sizes, int n_in,
                              void* d_out, int out_size, void* d_ws, size_t ws_size,
                              hipStream_t stream) {
    const float* x = (const float*)d_in[0];
    const float* D = (const float*)d_in[1];
    float* out = (float*)d_out;
    float* ws = (float*)d_ws;
    float* b  = ws;                        // NLAT f32 (channel-last)
    float* u  = b  + NLAT;                 // NLAT f32 (single buffer, in-place)
    float* DT = u  + NLAT;                 // 12288 f32
    float* Gf = DT + 12288;                // 81*4096 f32
    unsigned short* GAh = (unsigned short*)(Gf + 331776);
    unsigned short* GAl = GAh + 331776;
    unsigned short* DAh = GAl + 331776;
    unsigned short* DAl = DAh + 12288;
    unsigned short* A0  = DAl + 12288;     // 64*215296 ushorts
    unsigned short* A1  = A0 + (size_t)BATCH*AIMG;
    int* bar = (int*)(A1 + (size_t)BATCH*AIMG);   // 2 ints, 4B-aligned
    init_abuf_kernel<<<1824, 256, 0, stream>>>(A0, bar);  // halos + barrier
    prep_dt_kernel<<<48, 256, 0, stream>>>(D, DT);
    prep_gram_kernel<<<1296, 256, 0, stream>>>(DT, Gf);
    prep_packg_kernel<<<162, 256, 0, stream>>>(Gf, GAh, GAl);
    prep_packd_kernel<<<6, 256, 0, stream>>>(D, DAh, DAl);
    conv_b_kernel<<<BATCH*49, 256, 0, stream>>>(x, DAh, DAl, b, u, A0);  // iter 1
    lca_persist<<<NBLK, 256, 0, stream>>>(b, u, A0, A1, GAh, GAl, out, bar);
}

// Round 10
// 1707.546 us; speedup vs baseline: 6.5493x; 6.5493x over previous
//
#include <hip/hip_runtime.h>

#define BATCH 64
#define ATOMS 64
#define CIN 3
#define KS 8
#define H 224
#define W 224
#define OH 56
#define OW 56
#define NLAT (BATCH*ATOMS*OH*OW)   // 12,845,056
#define IMGSZ (OH*OW*ATOMS)        // 200,704 elems per image (channel-last)
#define LAM 0.1f
#define ETA 0.1f
// a-buffer: fp16, zero-padded halo, pre-swizzled: [img][R=0..57][C=0..57][64]
// element (R,C,n) at slot ((n>>3) ^ ((2R+C)&7))*8 + (n&7) within the 64.
// Every MFMA B-fragment (8 consecutive swizzled channels of one cell) is a
// contiguous 16B in global -> loaded directly, no LDS staging.
#define AROW 58
#define AIMG (AROW*AROW*64)        // 215,296 ushorts per image

typedef __attribute__((ext_vector_type(8)))  __bf16    bf16x8;
typedef __attribute__((ext_vector_type(8)))  _Float16  f16x8;
typedef __attribute__((ext_vector_type(16))) float     floatx16;

union FragU { uint4 u; bf16x8 v; };
union FragH { uint4 u; f16x8 v; };
union HalfBits { _Float16 h; unsigned short s; };

__device__ __forceinline__ float softthr(float u) {
    float p = u - LAM;  p = p > 0.f ? p : 0.f;
    float q = -u - LAM; q = q > 0.f ? q : 0.f;
    return p - q;
}
__device__ __forceinline__ unsigned short f2bf(float f) {   // RNE
    union { float f; unsigned int u; } c; c.f = f;
    unsigned int r = c.u + 0x7fffu + ((c.u >> 16) & 1u);
    return (unsigned short)(r >> 16);
}
__device__ __forceinline__ float bf2f(unsigned short h) {
    union { unsigned int u; float f; } c; c.u = ((unsigned int)h) << 16;
    return c.f;
}
__device__ __forceinline__ unsigned short f2h(float f) {    // fp16 bits, RNE
    HalfBits hb; hb.h = (_Float16)f; return hb.s;
}
__device__ __forceinline__ float h2f(unsigned short s) {
    HalfBits hb; hb.s = s; return (float)hb.h;
}
// swizzled ushort offset of atom n at padded coords (R,C) within an image
__device__ __forceinline__ size_t a_off(int img, int R, int C, int n) {
    return (((size_t)img*AROW + R)*AROW + C)*64
         + ((((n >> 3) ^ ((2*R + C) & 7)) << 3) | (n & 7));
}

// Zero the halo border cells of BOTH a-buffers (contiguous A0|A1).
__global__ void init_abuf_kernel(unsigned short* __restrict__ A) {
    int idx = blockIdx.x * 256 + threadIdx.x;   // 128 img-buf x 228 cells x 16 quads
    int ib = idx / 3648, r = idx % 3648;
    int cell = r >> 4, q = r & 15;
    int R, C;
    if      (cell < 58)  { R = 0;  C = cell; }
    else if (cell < 116) { R = 57; C = cell - 58; }
    else if (cell < 172) { R = cell - 116 + 1; C = 0; }
    else                 { R = cell - 172 + 1; C = 57; }
    size_t off = (size_t)ib*AIMG + ((size_t)R*AROW + C)*64 + q*4;
    *(ushort4*)(A + off) = make_ushort4(0, 0, 0, 0);
}

// DT[((c*8+y)*8+x)*64 + m] = D[m,c,y,x]
__global__ void prep_dt_kernel(const float* __restrict__ D,
                               float* __restrict__ DT) {
    int idx = blockIdx.x * 256 + threadIdx.x;
    if (idx < CIN*KS*KS*ATOMS) {
        int m = idx & 63;
        int r = idx >> 6;
        int xk = r & 7, y = (r >> 3) & 7, c = r >> 6;
        DT[idx] = D[((m*CIN + c)*KS + y)*KS + xk];
    }
}

// 9 table-sets (inclusion-exclusion for boundary classes), 9 dpq each.
__global__ void prep_gram_kernel(const float* __restrict__ DT,
                                 float* __restrict__ G) {
    int blk = blockIdx.x;              // td*16 + nchunk
    int td = blk >> 4;
    int tbl = td / 9, dpq = td % 9;
    int dp = dpq / 3, dq = dpq % 3;
    int di = 1 - dp, dj = 1 - dq;
    int ylo = (0 > -4*di) ? 0 : -4*di;
    int yhi = (8 < 8-4*di) ? 8 : 8-4*di;
    int xlo = (0 > -4*dj) ? 0 : -4*dj;
    int xhi = (8 < 8-4*dj) ? 8 : 8-4*dj;
    if (tbl==1 || tbl==5 || tbl==6) { if (yhi > 2) yhi = 2; }
    if (tbl==2 || tbl==7 || tbl==8) { if (ylo < 6) ylo = 6; }
    if (tbl==3 || tbl==5 || tbl==7) { if (xhi > 2) xhi = 2; }
    if (tbl==4 || tbl==6 || tbl==8) { if (xlo < 6) xlo = 6; }
    float sign = (tbl >= 1 && tbl <= 4) ? -1.f : 1.f;
    int t = threadIdx.x;
    int m = t & 63;
    int n = (blk & 15)*4 + (t >> 6);
    float s = 0.f;
    for (int c = 0; c < CIN; ++c)
        for (int y = ylo; y < yhi; ++y)
            for (int x = xlo; x < xhi; ++x)
                s += DT[((c*8+y)*8+x)*64 + m] *
                     DT[((c*8+y+4*di)*8 + (x+4*dj))*64 + n];
    G[td*4096 + n*64 + m] = sign * s;
}

// Pack G into MFMA A-operand layout, split FP16 hi/lo.
__global__ void prep_packg_kernel(const float* __restrict__ G,
                                  unsigned short* __restrict__ GAh,
                                  unsigned short* __restrict__ GAl) {
    int g = blockIdx.x * 256 + threadIdx.x;      // 162*256 = 41472 groups
    int lane = g & 63;
    int r = g >> 6;
    int kstep = r & 3; r >>= 2;
    int mhalf = r & 1; int td = r >> 1;          // tbl*9+dpq
    int m = mhalf*32 + (lane & 31);
    int n = kstep*16 + (lane >> 5)*8;
    const float* src = G + td*4096 + n*64 + m;
#pragma unroll
    for (int j = 0; j < 8; ++j) {
        float v = src[j*64];
        unsigned short h = f2h(v);
        GAh[g*8 + j] = h;
        GAl[g*8 + j] = f2h(v - h2f(h));
    }
}

// Pack D into MFMA A-layout for conv_b: K=192, k = c*64+y*8+x. (bf16 split)
__global__ void prep_packd_kernel(const float* __restrict__ D,
                                  unsigned short* __restrict__ DAh,
                                  unsigned short* __restrict__ DAl) {
    int g = blockIdx.x * 256 + threadIdx.x;
    if (g >= 1536) return;
    int lane = g & 63;
    int r = g >> 6;
    int kstep = r % 12, mhalf = r / 12;
    int m = mhalf*32 + (lane & 31);
    int k0 = kstep*16 + (lane >> 5)*8;
#pragma unroll
    for (int j = 0; j < 8; ++j) {
        float v = D[m*192 + k0 + j];
        unsigned short h = f2bf(v);
        DAh[g*8 + j] = h;
        DAl[g*8 + j] = f2bf(v - bf2f(h));
    }
}

// b = conv2d(x, D, stride4, pad2); u = 0.1*b; a1 = softthr(u) -> A0 (swizzled).
__global__ __launch_bounds__(256) void conv_b_kernel(
        const float* __restrict__ x,
        const unsigned short* __restrict__ DAh,
        const unsigned short* __restrict__ DAl,
        float* __restrict__ b, float* __restrict__ u,
        unsigned short* __restrict__ A0) {
    __shared__ __align__(16) unsigned short xth[CIN*36*36];
    __shared__ __align__(16) unsigned short xtl[CIN*36*36];
    __shared__ float ot[64*65];
    int blk = blockIdx.x;
    int img = blk / 49, tile = blk % 49;
    int i0 = (tile / 7) * 8, j0 = (tile % 7) * 8;
    int t = threadIdx.x;
    int r0 = 4*i0 - 2, c0 = 4*j0 - 2;
    for (int f = t; f < CIN*36*36; f += 256) {
        int cc = f / 1296, rem = f % 1296;
        int rr = rem / 36, qq = rem % 36;
        int Y = r0 + rr, X = c0 + qq;
        float v = 0.f;
        if (Y >= 0 && Y < H && X >= 0 && X < W)
            v = x[((img*CIN + cc)*H + Y)*W + X];
        unsigned short h = f2bf(v);
        xth[f] = h;
        xtl[f] = f2bf(v - bf2f(h));
    }
    __syncthreads();
    int lane = t & 63, wave = t >> 6;
    int mhalf = wave & 1, poshalf = wave >> 1;
    int pos = poshalf*32 + (lane & 31), pi = pos >> 3, pj = pos & 7;
    int khalf = lane >> 5;
    floatx16 acc;
#pragma unroll
    for (int i = 0; i < 16; ++i) acc[i] = 0.f;
    const uint4* Ah4 = (const uint4*)DAh;
    const uint4* Al4 = (const uint4*)DAl;
#pragma unroll 3
    for (int kstep = 0; kstep < 12; ++kstep) {
        int k0 = kstep*16 + khalf*8;
        int cc = k0 >> 6, yy = (k0 >> 3) & 7;
        int boff = cc*1296 + (4*pi + yy)*36 + 4*pj;
        FragU ah, al, bh, bl;
        ah.u = Ah4[(mhalf*12 + kstep)*64 + lane];
        al.u = Al4[(mhalf*12 + kstep)*64 + lane];
        const uint2* ph = (const uint2*)(xth + boff);
        uint2 h0 = ph[0], h1 = ph[1];
        bh.u = make_uint4(h0.x, h0.y, h1.x, h1.y);
        const uint2* pl = (const uint2*)(xtl + boff);
        uint2 l0 = pl[0], l1 = pl[1];
        bl.u = make_uint4(l0.x, l0.y, l1.x, l1.y);
        acc = __builtin_amdgcn_mfma_f32_32x32x16_bf16(ah.v, bh.v, acc, 0, 0, 0);
        acc = __builtin_amdgcn_mfma_f32_32x32x16_bf16(ah.v, bl.v, acc, 0, 0, 0);
        acc = __builtin_amdgcn_mfma_f32_32x32x16_bf16(al.v, bh.v, acc, 0, 0, 0);
    }
#pragma unroll
    for (int r16 = 0; r16 < 16; ++r16) {
        int row = (r16 & 3) + 8*(r16 >> 2) + 4*khalf;
        ot[(mhalf*32 + row)*65 + pos] = acc[r16];
    }
    __syncthreads();
    int m = t & 63;
    float* bp = b + (size_t)img*IMGSZ;
    float* up = u + (size_t)img*IMGSZ;
#pragma unroll
    for (int e = 0; e < 16; ++e) {
        int pp = e*4 + (t >> 6);
        int gi = i0 + (pp >> 3), gj = j0 + (pp & 7);
        int gidx = (gi*OW + gj)*64 + m;
        float v = ot[m*65 + pp];
        bp[gidx] = v;
        float uv = ETA * v;
        up[gidx] = uv;
        A0[a_off(img, gi + 1, gj + 1, m)] = f2h(softthr(uv));
    }
}

// ---- MFMA helpers: A from Gram tables, B straight from global a-buffer ----
__device__ __forceinline__ void load_a(uint4 (&A)[9], const uint4* __restrict__ Gh4,
                                       const uint4* __restrict__ Gl4,
                                       int txoff, int bb, int mhalf, int lane) {
    int dq = bb >> 2, ks = bb & 3;
#pragma unroll
    for (int dp = 0; dp < 3; ++dp) {
        int abase = (((3*dp + dq)*2 + mhalf)*4 + ks)*64 + lane;
        A[dp*3+0] = Gh4[abase];
        A[dp*3+1] = Gl4[abase];
        A[dp*3+2] = Gh4[txoff + abase];
    }
}
// B-fragment: padded cell (R = i0+p, C = pjx+dq), k-group kg2, from global.
__device__ __forceinline__ void load_bg(uint4 (&B)[4], const uint4* __restrict__ Ab4,
                                        int bb, int khalf, int i0, int pjx) {
    int dq = bb >> 2, ks = bb & 3;
    int kg2 = ks*2 + khalf;
    int C = pjx + dq;
#pragma unroll
    for (int p = 0; p < 4; ++p) {
        int R = i0 + p;
        int key = (2*R + C) & 7;
        B[p] = Ab4[(R*AROW + C)*8 + (kg2 ^ key)];
    }
}
__device__ __forceinline__ void do_mfma(floatx16& acc0, floatx16& acc1,
                                        const uint4 (&A)[9], const uint4 (&B)[4],
                                        unsigned msel) {
    __builtin_amdgcn_s_setprio(1);
#pragma unroll
    for (int dp = 0; dp < 3; ++dp) {
        FragH a0, a1, ax, b0, b1, bm0, bm1;
        a0.u = A[dp*3+0]; a1.u = A[dp*3+1]; ax.u = A[dp*3+2];
        b0.u = B[dp]; b1.u = B[dp+1];
        bm0.u = make_uint4(b0.u.x & msel, b0.u.y & msel,
                           b0.u.z & msel, b0.u.w & msel);
        bm1.u = make_uint4(b1.u.x & msel, b1.u.y & msel,
                           b1.u.z & msel, b1.u.w & msel);
        acc0 = __builtin_amdgcn_mfma_f32_32x32x16_f16(a0.v, b0.v, acc0, 0,0,0);
        acc1 = __builtin_amdgcn_mfma_f32_32x32x16_f16(a0.v, b1.v, acc1, 0,0,0);
        acc0 = __builtin_amdgcn_mfma_f32_32x32x16_f16(a1.v, b0.v, acc0, 0,0,0);
        acc1 = __builtin_amdgcn_mfma_f32_32x32x16_f16(a1.v, b1.v, acc1, 0,0,0);
        acc0 = __builtin_amdgcn_mfma_f32_32x32x16_f16(ax.v, bm0.v, acc0, 0,0,0);
        acc1 = __builtin_amdgcn_mfma_f32_32x32x16_f16(ax.v, bm1.v, acc1, 0,0,0);
    }
    __builtin_amdgcn_s_setprio(0);
}

// One LCA step on a 2-row band. R13: NO LDS staging — B-fragments are read
// directly from the pre-swizzled global a-buffer (L2-resident via XCD-swizzle:
// 8 images x 430KB = 3.4MB per XCD L2). Single barrier (output transpose).
// Numerics identical to the R5/R6 passing versions.
__global__ __launch_bounds__(256, 4) void lca_iter_kernel(
        const float* __restrict__ b, float* __restrict__ u,
        const unsigned short* __restrict__ Ain,
        unsigned short* __restrict__ Aout,
        const unsigned short* __restrict__ GAh,
        const unsigned short* __restrict__ GAl,
        float* __restrict__ out, int last) {
    __shared__ float ot[112*65];                 // 29120 B
    int blk = blockIdx.x;
    // bijective XCD chunking: 1792 = 8*224; bands of one image share an XCD
    int task = (blk & 7)*224 + (blk >> 3);
    int img = task / 28, bandi = task % 28;
    int i0 = bandi*2;                            // padded top row of 4-row window
    int t = threadIdx.x;
    int lane = t & 63, wave = t >> 6;
    int mhalf = wave & 1, cgrp = wave >> 1;
    int khalf = lane >> 5, cl = lane & 31;
    int pj = cgrp*32 + cl;
    int pjx = (pj < 56) ? pj : 0;
    floatx16 acc0, acc1;
#pragma unroll
    for (int i = 0; i < 16; ++i) { acc0[i] = 0.f; acc1[i] = 0.f; }
    const uint4* Gh4 = (const uint4*)GAh;
    const uint4* Gl4 = (const uint4*)GAl;
    const uint4* Ab4 = (const uint4*)(Ain + (size_t)img*AIMG);
    int tbx = (cgrp == 0) ? 3 : 4;
    int txoff = (tbx*9)*512;
    unsigned msel = (cl == ((cgrp == 0) ? 0 : 23)) ? 0xFFFFFFFFu : 0u;
    bool edge = (bandi == 0) || (bandi == 27);
    if (!edge) {
        uint4 Aa[9], Ab[9], Ba[4], Bb[4];
        load_a(Aa, Gh4, Gl4, txoff, 0, mhalf, lane);
        load_bg(Ba, Ab4, 0, khalf, i0, pjx);
#pragma unroll 1
        for (int it2 = 0; it2 < 6; ++it2) {
            int bb = it2*2;
            load_a(Ab, Gh4, Gl4, txoff, bb+1, mhalf, lane);
            load_bg(Bb, Ab4, bb+1, khalf, i0, pjx);
            do_mfma(acc0, acc1, Aa, Ba, msel);
            if (it2 < 5) {
                load_a(Aa, Gh4, Gl4, txoff, bb+2, mhalf, lane);
                load_bg(Ba, Ab4, bb+2, khalf, i0, pjx);
            }
            do_mfma(acc0, acc1, Ab, Bb, msel);
        }
    } else {
        int ymask, tby, tbc;
        if (bandi == 0) { ymask = 1; tby = 1; tbc = (cgrp == 0) ? 5 : 6; }
        else            { ymask = 2; tby = 2; tbc = (cgrp == 0) ? 7 : 8; }
#pragma unroll 1
        for (int dq = 0; dq < 3; ++dq) {
#pragma unroll 1
            for (int kstep = 0; kstep < 4; ++kstep) {
                int kg2 = kstep*2 + khalf;
#pragma unroll
                for (int dp = 0; dp < 3; ++dp) {
                    int R0 = i0 + dp, C = pjx + dq;
                    FragH B0, B1;
                    B0.u = Ab4[(R0*AROW + C)*8 + (kg2 ^ ((2*R0 + C) & 7))];
                    B1.u = Ab4[((R0+1)*AROW + C)*8 + (kg2 ^ ((2*R0 + 2 + C) & 7))];
                    for (int tm = 0; tm < 6; ++tm) {
                        int td = (tm < 2) ? 0 : (tm == 2) ? tbx : (tm < 5) ? tby : tbc;
                        const uint4* Ap = ((tm == 1) || (tm == 4)) ? Gl4 : Gh4;
                        bool masked = (tm == 2) || (tm == 5);
                        int am = (tm < 3) ? 3 : ymask;
                        FragH a;
                        a.u = Ap[(((td*9 + 3*dp + dq)*2 + mhalf)*4 + kstep)*64 + lane];
                        if (!masked) {
                            if (am & 1)
                                acc0 = __builtin_amdgcn_mfma_f32_32x32x16_f16(a.v, B0.v, acc0, 0,0,0);
                            if (am & 2)
                                acc1 = __builtin_amdgcn_mfma_f32_32x32x16_f16(a.v, B1.v, acc1, 0,0,0);
                        } else {
                            if (am & 1) {
                                FragH bm;
                                bm.u = make_uint4(B0.u.x & msel, B0.u.y & msel,
                                                  B0.u.z & msel, B0.u.w & msel);
                                acc0 = __builtin_amdgcn_mfma_f32_32x32x16_f16(a.v, bm.v, acc0, 0,0,0);
                            }
                            if (am & 2) {
                                FragH bm;
                                bm.u = make_uint4(B1.u.x & msel, B1.u.y & msel,
                                                  B1.u.z & msel, B1.u.w & msel);
                                acc1 = __builtin_amdgcn_mfma_f32_32x32x16_f16(a.v, bm.v, acc1, 0,0,0);
                            }
                        }
                    }
                }
            }
        }
    }
    // Output transpose (single barrier of the kernel).
    if (pj < 56) {
#pragma unroll
        for (int r16 = 0; r16 < 16; ++r16) {
            int row = (r16 & 3) + 8*(r16 >> 2) + 4*khalf;
            int m = mhalf*32 + row;
            ot[pj*65 + m] = acc0[r16];
            ot[(56 + pj)*65 + m] = acc1[r16];
        }
    }
    __syncthreads();
    const float* bp = b + (size_t)img*IMGSZ;
    float* up = u + (size_t)img*IMGSZ;          // in-place state update
#pragma unroll 7
    for (int pass = 0; pass < 28; ++pass) {     // 2*56*64 elems, lane = n
        int idx = pass*256 + t;
        int n = idx & 63;
        int rest = idx >> 6;                    // 0..111
        int pi = (rest >= 56) ? 1 : 0;
        int j = rest - 56*pi;
        int g = ((i0 + pi)*OW + j)*64 + n;
        float uo = up[g];
        float gram = ot[(pi*56 + j)*65 + n];
        float un = uo + ETA * (bp[g] - uo - gram + softthr(uo));
        if (last) {
            out[(((size_t)img*ATOMS + n)*OH + (i0 + pi))*OW + j] = softthr(un);
        } else {
            up[g] = un;
            Aout[a_off(img, i0 + pi + 1, j + 1, n)] = f2h(softthr(un));
        }
    }
}

extern "C" void kernel_launch(void* const* d_in, const int* in_sizes, int n_in,
                              void* d_out, int out_size, void* d_ws, size_t ws_size,
                              hipStream_t stream) {
    const float* x = (const float*)d_in[0];
    const float* D = (const float*)d_in[1];
    float* out = (float*)d_out;
    float* ws = (float*)d_ws;
    float* b  = ws;                        // NLAT f32 (channel-last)
    float* u  = b  + NLAT;                 // NLAT f32 (single buffer, in-place)
    float* DT = u  + NLAT;                 // 12288 f32
    float* Gf = DT + 12288;                // 81*4096 f32
    unsigned short* GAh = (unsigned short*)(Gf + 331776);
    unsigned short* GAl = GAh + 331776;
    unsigned short* DAh = GAl + 331776;
    unsigned short* DAl = DAh + 12288;
    unsigned short* A0  = DAl + 12288;     // 64*215296 ushorts
    unsigned short* A1  = A0 + (size_t)BATCH*AIMG;
    init_abuf_kernel<<<1824, 256, 0, stream>>>(A0);   // zero halo of A0+A1
    prep_dt_kernel<<<48, 256, 0, stream>>>(D, DT);
    prep_gram_kernel<<<1296, 256, 0, stream>>>(DT, Gf);
    prep_packg_kernel<<<162, 256, 0, stream>>>(Gf, GAh, GAl);
    prep_packd_kernel<<<6, 256, 0, stream>>>(D, DAh, DAl);
    conv_b_kernel<<<BATCH*49, 256, 0, stream>>>(x, DAh, DAl, b, u, A0);  // iter 1
    unsigned short* ain = A0; unsigned short* aout = A1;
    for (int it = 0; it < 9; ++it) {       // iterations 2..10 (iter 1 folded)
        int last = (it == 8);
        lca_iter_kernel<<<BATCH*28, 256, 0, stream>>>(b, u, ain, aout, GAh, GAl, out, last);
        unsigned short* tmp = ain; ain = aout; aout = tmp;
    }
}

// Round 11
// 1187.687 us; speedup vs baseline: 9.4160x; 1.4377x over previous
//
#include <hip/hip_runtime.h>

#define BATCH 64
#define ATOMS 64
#define CIN 3
#define KS 8
#define H 224
#define W 224
#define OH 56
#define OW 56
#define NLAT (BATCH*ATOMS*OH*OW)   // 12,845,056
#define IMGSZ (OH*OW*ATOMS)        // 200,704 elems per image (channel-last)
#define LAM 0.1f
#define ETA 0.1f
// a-buffer: fp16, zero-padded halo, pre-swizzled: [img][R=0..57][C=0..57][64]
// element (R,C,n) at slot ((n>>3) ^ ((2R+C)&7))*8 + (n&7) within the 64.
// Per-image stride includes a 256-ushort (512 B) tail pad so the 44-chunk
// DMA overread of the last band stays in-bounds.
#define AROW 58
#define AIMG (AROW*AROW*64 + 256)  // 215,552 ushorts per image (padded)

typedef __attribute__((ext_vector_type(8)))  __bf16    bf16x8;
typedef __attribute__((ext_vector_type(8)))  _Float16  f16x8;
typedef __attribute__((ext_vector_type(16))) float     floatx16;

union FragU { uint4 u; bf16x8 v; };
union FragH { uint4 u; f16x8 v; };
union HalfBits { _Float16 h; unsigned short s; };

__device__ __forceinline__ float softthr(float u) {
    float p = u - LAM;  p = p > 0.f ? p : 0.f;
    float q = -u - LAM; q = q > 0.f ? q : 0.f;
    return p - q;
}
__device__ __forceinline__ unsigned short f2bf(float f) {   // RNE
    union { float f; unsigned int u; } c; c.f = f;
    unsigned int r = c.u + 0x7fffu + ((c.u >> 16) & 1u);
    return (unsigned short)(r >> 16);
}
__device__ __forceinline__ float bf2f(unsigned short h) {
    union { unsigned int u; float f; } c; c.u = ((unsigned int)h) << 16;
    return c.f;
}
__device__ __forceinline__ unsigned short f2h(float f) {    // fp16 bits, RNE
    HalfBits hb; hb.h = (_Float16)f; return hb.s;
}
__device__ __forceinline__ float h2f(unsigned short s) {
    HalfBits hb; hb.s = s; return (float)hb.h;
}
// swizzled ushort offset of atom n at padded coords (R,C) within an image
__device__ __forceinline__ size_t a_off(int img, int R, int C, int n) {
    return (size_t)img*AIMG + ((size_t)R*AROW + C)*64
         + ((((n >> 3) ^ ((2*R + C) & 7)) << 3) | (n & 7));
}

// Merged independent prep: blocks [0,1824) zero a-buffer halos,
// [1824,1872) build DT, [1872,1878) pack D (bf16 split).
__global__ void prep_a_kernel(const float* __restrict__ D,
                              unsigned short* __restrict__ A,
                              float* __restrict__ DT,
                              unsigned short* __restrict__ DAh,
                              unsigned short* __restrict__ DAl) {
    int bb = blockIdx.x;
    if (bb < 1824) {
        int idx = bb * 256 + threadIdx.x;   // 128 img-buf x 228 cells x 16 quads
        int ib = idx / 3648, r = idx % 3648;
        int cell = r >> 4, q = r & 15;
        int R, C;
        if      (cell < 58)  { R = 0;  C = cell; }
        else if (cell < 116) { R = 57; C = cell - 58; }
        else if (cell < 172) { R = cell - 116 + 1; C = 0; }
        else                 { R = cell - 172 + 1; C = 57; }
        size_t off = (size_t)ib*AIMG + ((size_t)R*AROW + C)*64 + q*4;
        *(ushort4*)(A + off) = make_ushort4(0, 0, 0, 0);
    } else if (bb < 1872) {
        int idx = (bb - 1824) * 256 + threadIdx.x;
        if (idx < CIN*KS*KS*ATOMS) {
            int m = idx & 63;
            int r = idx >> 6;
            int xk = r & 7, y = (r >> 3) & 7, c = r >> 6;
            DT[idx] = D[((m*CIN + c)*KS + y)*KS + xk];
        }
    } else {
        int g = (bb - 1872) * 256 + threadIdx.x;
        if (g >= 1536) return;
        int lane = g & 63;
        int r = g >> 6;
        int kstep = r % 12, mhalf = r / 12;
        int m = mhalf*32 + (lane & 31);
        int k0 = kstep*16 + (lane >> 5)*8;
#pragma unroll
        for (int j = 0; j < 8; ++j) {
            float v = D[m*192 + k0 + j];
            unsigned short h = f2bf(v);
            DAh[g*8 + j] = h;
            DAl[g*8 + j] = f2bf(v - bf2f(h));
        }
    }
}

// 9 table-sets (inclusion-exclusion for boundary classes), 9 dpq each.
// tbl: 0=T0(all) 1=-dY1 2=-dY2 3=-dX1 4=-dX2 5=+dC11 6=+dC12 7=+dC21 8=+dC22
__global__ void prep_gram_kernel(const float* __restrict__ DT,
                                 float* __restrict__ G) {
    int blk = blockIdx.x;              // td*16 + nchunk
    int td = blk >> 4;
    int tbl = td / 9, dpq = td % 9;
    int dp = dpq / 3, dq = dpq % 3;
    int di = 1 - dp, dj = 1 - dq;
    int ylo = (0 > -4*di) ? 0 : -4*di;
    int yhi = (8 < 8-4*di) ? 8 : 8-4*di;
    int xlo = (0 > -4*dj) ? 0 : -4*dj;
    int xhi = (8 < 8-4*dj) ? 8 : 8-4*dj;
    if (tbl==1 || tbl==5 || tbl==6) { if (yhi > 2) yhi = 2; }
    if (tbl==2 || tbl==7 || tbl==8) { if (ylo < 6) ylo = 6; }
    if (tbl==3 || tbl==5 || tbl==7) { if (xhi > 2) xhi = 2; }
    if (tbl==4 || tbl==6 || tbl==8) { if (xlo < 6) xlo = 6; }
    float sign = (tbl >= 1 && tbl <= 4) ? -1.f : 1.f;
    int t = threadIdx.x;
    int m = t & 63;
    int n = (blk & 15)*4 + (t >> 6);
    float s = 0.f;
    for (int c = 0; c < CIN; ++c)
        for (int y = ylo; y < yhi; ++y)
            for (int x = xlo; x < xhi; ++x)
                s += DT[((c*8+y)*8+x)*64 + m] *
                     DT[((c*8+y+4*di)*8 + (x+4*dj))*64 + n];
    G[td*4096 + n*64 + m] = sign * s;
}

// Pack G into MFMA A-operand layout, split FP16 hi/lo.
__global__ void prep_packg_kernel(const float* __restrict__ G,
                                  unsigned short* __restrict__ GAh,
                                  unsigned short* __restrict__ GAl) {
    int g = blockIdx.x * 256 + threadIdx.x;      // 162*256 = 41472 groups
    int lane = g & 63;
    int r = g >> 6;
    int kstep = r & 3; r >>= 2;
    int mhalf = r & 1; int td = r >> 1;          // tbl*9+dpq
    int m = mhalf*32 + (lane & 31);
    int n = kstep*16 + (lane >> 5)*8;
    const float* src = G + td*4096 + n*64 + m;
#pragma unroll
    for (int j = 0; j < 8; ++j) {
        float v = src[j*64];
        unsigned short h = f2h(v);
        GAh[g*8 + j] = h;
        GAl[g*8 + j] = f2h(v - h2f(h));
    }
}

// b = conv2d(x, D, stride4, pad2); u = 0.1*b; a1 = softthr(u) -> A0 (swizzled).
// Output CHANNEL-LAST [i][j][n].
__global__ __launch_bounds__(256) void conv_b_kernel(
        const float* __restrict__ x,
        const unsigned short* __restrict__ DAh,
        const unsigned short* __restrict__ DAl,
        float* __restrict__ b, float* __restrict__ u,
        unsigned short* __restrict__ A0) {
    __shared__ __align__(16) unsigned short xth[CIN*36*36];
    __shared__ __align__(16) unsigned short xtl[CIN*36*36];
    __shared__ float ot[64*65];
    int blk0 = blockIdx.x;
    int blk = (blk0 & 7)*392 + (blk0 >> 3);      // bijective XCD swizzle (3136=8*392)
    int img = blk / 49, tile = blk % 49;
    int i0 = (tile / 7) * 8, j0 = (tile % 7) * 8;
    int t = threadIdx.x;
    int r0 = 4*i0 - 2, c0 = 4*j0 - 2;
    for (int f = t; f < CIN*36*36; f += 256) {
        int cc = f / 1296, rem = f % 1296;
        int rr = rem / 36, qq = rem % 36;
        int Y = r0 + rr, X = c0 + qq;
        float v = 0.f;
        if (Y >= 0 && Y < H && X >= 0 && X < W)
            v = x[((img*CIN + cc)*H + Y)*W + X];
        unsigned short h = f2bf(v);
        xth[f] = h;
        xtl[f] = f2bf(v - bf2f(h));
    }
    __syncthreads();
    int lane = t & 63, wave = t >> 6;
    int mhalf = wave & 1, poshalf = wave >> 1;
    int pos = poshalf*32 + (lane & 31), pi = pos >> 3, pj = pos & 7;
    int khalf = lane >> 5;
    floatx16 acc;
#pragma unroll
    for (int i = 0; i < 16; ++i) acc[i] = 0.f;
    const uint4* Ah4 = (const uint4*)DAh;
    const uint4* Al4 = (const uint4*)DAl;
#pragma unroll 3
    for (int kstep = 0; kstep < 12; ++kstep) {
        int k0 = kstep*16 + khalf*8;
        int cc = k0 >> 6, yy = (k0 >> 3) & 7;
        int boff = cc*1296 + (4*pi + yy)*36 + 4*pj;
        FragU ah, al, bh, bl;
        ah.u = Ah4[(mhalf*12 + kstep)*64 + lane];
        al.u = Al4[(mhalf*12 + kstep)*64 + lane];
        const uint2* ph = (const uint2*)(xth + boff);
        uint2 h0 = ph[0], h1 = ph[1];
        bh.u = make_uint4(h0.x, h0.y, h1.x, h1.y);
        const uint2* pl = (const uint2*)(xtl + boff);
        uint2 l0 = pl[0], l1 = pl[1];
        bl.u = make_uint4(l0.x, l0.y, l1.x, l1.y);
        acc = __builtin_amdgcn_mfma_f32_32x32x16_bf16(ah.v, bh.v, acc, 0, 0, 0);
        acc = __builtin_amdgcn_mfma_f32_32x32x16_bf16(ah.v, bl.v, acc, 0, 0, 0);
        acc = __builtin_amdgcn_mfma_f32_32x32x16_bf16(al.v, bh.v, acc, 0, 0, 0);
    }
#pragma unroll
    for (int r16 = 0; r16 < 16; ++r16) {
        int row = (r16 & 3) + 8*(r16 >> 2) + 4*khalf;
        ot[(mhalf*32 + row)*65 + pos] = acc[r16];
    }
    __syncthreads();
    // channel-last epilogue: lane = channel -> 256B contiguous stores
    int m = t & 63;
    float* bp = b + (size_t)img*IMGSZ;
    float* up = u + (size_t)img*IMGSZ;
#pragma unroll
    for (int e = 0; e < 16; ++e) {
        int pp = e*4 + (t >> 6);
        int gi = i0 + (pp >> 3), gj = j0 + (pp & 7);
        int gidx = (gi*OW + gj)*64 + m;
        float v = ot[m*65 + pp];
        bp[gidx] = v;
        float uv = ETA * v;
        up[gidx] = uv;
        A0[a_off(img, gi + 1, gj + 1, m)] = f2h(softthr(uv));
    }
}

// ---- interior fast-path helpers: double-buffered register pipeline ----
__device__ __forceinline__ void load_a(uint4 (&A)[9], const uint4* __restrict__ Gh4,
                                       const uint4* __restrict__ Gl4,
                                       int txoff, int bb, int mhalf, int lane) {
    int dq = bb >> 2, ks = bb & 3;
#pragma unroll
    for (int dp = 0; dp < 3; ++dp) {
        int abase = (((3*dp + dq)*2 + mhalf)*4 + ks)*64 + lane;
        A[dp*3+0] = Gh4[abase];
        A[dp*3+1] = Gl4[abase];
        A[dp*3+2] = Gh4[txoff + abase];
    }
}
__device__ __forceinline__ void load_b(uint4 (&B)[4], const uint4* __restrict__ B4h,
                                       int bb, int khalf, int base) {
    int dq = bb >> 2, ks = bb & 3;
    int kg2 = ks*2 + khalf;
#pragma unroll
    for (int p = 0; p < 4; ++p) {
        int rc = p*58 + base + dq;
        B[p] = B4h[rc*8 + (kg2 ^ (rc & 7))];
    }
}
__device__ __forceinline__ void do_mfma(floatx16& acc0, floatx16& acc1,
                                        const uint4 (&A)[9], const uint4 (&B)[4],
                                        unsigned msel) {
    __builtin_amdgcn_s_setprio(1);
#pragma unroll
    for (int dp = 0; dp < 3; ++dp) {
        FragH a0, a1, ax, b0, b1, bm0, bm1;
        a0.u = A[dp*3+0]; a1.u = A[dp*3+1]; ax.u = A[dp*3+2];
        b0.u = B[dp]; b1.u = B[dp+1];
        bm0.u = make_uint4(b0.u.x & msel, b0.u.y & msel,
                           b0.u.z & msel, b0.u.w & msel);
        bm1.u = make_uint4(b1.u.x & msel, b1.u.y & msel,
                           b1.u.z & msel, b1.u.w & msel);
        acc0 = __builtin_amdgcn_mfma_f32_32x32x16_f16(a0.v, b0.v, acc0, 0,0,0);
        acc1 = __builtin_amdgcn_mfma_f32_32x32x16_f16(a0.v, b1.v, acc1, 0,0,0);
        acc0 = __builtin_amdgcn_mfma_f32_32x32x16_f16(a1.v, b0.v, acc0, 0,0,0);
        acc1 = __builtin_amdgcn_mfma_f32_32x32x16_f16(a1.v, b1.v, acc1, 0,0,0);
        acc0 = __builtin_amdgcn_mfma_f32_32x32x16_f16(ax.v, bm0.v, acc0, 0,0,0);
        acc1 = __builtin_amdgcn_mfma_f32_32x32x16_f16(ax.v, bm1.v, acc1, 0,0,0);
    }
    __builtin_amdgcn_s_setprio(0);
}

// One LCA step on a 4-row x 56-col band, 512 threads = 8 waves
// {mhalf x2, cgrp x2, rowhalf x2}; each wave keeps the 2-acc structure.
// R14 = R12(best, 1119us) + bijective XCD swizzle (896=8*112: each XCD
// serves 8 whole images -> halo re-reads and Gram tables stay L2-local).
__global__ __launch_bounds__(512) void lca_iter_kernel(
        const float* __restrict__ b, float* __restrict__ u,
        const unsigned short* __restrict__ Ain,
        unsigned short* __restrict__ Aout,
        const unsigned short* __restrict__ GAh,
        const unsigned short* __restrict__ GAl,
        float* __restrict__ out, int last) {
    __shared__ __align__(1024) unsigned char smem[45056];  // 44 KB stage / 29120 ot
    unsigned short* at2h = (unsigned short*)smem;          // [rc][swizzled n]
    int blk0 = blockIdx.x;
    int blk = (blk0 & 7)*112 + (blk0 >> 3);      // bijective XCD swizzle (896=8*112)
    int img = blk / 14, bandq = blk % 14;
    int i0o = bandq*4;                 // first output row of the band
    int t = threadIdx.x;
    // Phase 1: padded rows R = 4*bandq .. +5 (6 rows x 58 x 64 fp16),
    // contiguous in global -> linear LDS DMA (44 x 1KB chunks; last chunk
    // overreads 512 B into the per-image pad).
    {
        const char* gbase = (const char*)(Ain + (size_t)img*AIMG
                              + (size_t)i0o*AROW*64) + (t & 63)*16;
        char* lbase = (char*)smem;
        int w = t >> 6;
        for (int c = w; c < 44; c += 8) {
            __builtin_amdgcn_global_load_lds(
                (const __attribute__((address_space(1))) unsigned int*)(gbase + c*1024),
                (__attribute__((address_space(3))) unsigned int*)(lbase + c*1024),
                16, 0, 0);
        }
    }
    __syncthreads();
    int lane = t & 63, wave = t >> 6;
    int mhalf = wave & 1, cgrp = (wave >> 1) & 1, rowhalf = wave >> 2;
    int khalf = lane >> 5, cl = lane & 31;
    int pj = cgrp*32 + cl;
    int pjx = (pj < 56) ? pj : 0;                // clamp invalid columns
    int rb58 = rowhalf*2*58;                     // B-row base offset in LDS
    floatx16 acc0, acc1;
#pragma unroll
    for (int i = 0; i < 16; ++i) { acc0[i] = 0.f; acc1[i] = 0.f; }
    const uint4* Gh4 = (const uint4*)GAh;
    const uint4* Gl4 = (const uint4*)GAl;
    const uint4* B4h = (const uint4*)at2h;
    int tbx = (cgrp == 0) ? 3 : 4;               // X boundary table
    int txoff = (tbx*9)*512;
    unsigned msel = (cl == ((cgrp == 0) ? 0 : 23)) ? 0xFFFFFFFFu : 0u;
    bool edgewave = (bandq == 0 && rowhalf == 0) || (bandq == 13 && rowhalf == 1);
    if (!edgewave) {
        // ---- interior fast path: reg-double-buffered pipeline, 12 bodies ----
        uint4 Aa[9], Ab[9], Ba[4], Bb[4];
        load_a(Aa, Gh4, Gl4, txoff, 0, mhalf, lane);
        load_b(Ba, B4h, 0, khalf, rb58 + pjx);
#pragma unroll 1
        for (int it2 = 0; it2 < 6; ++it2) {
            int bb = it2*2;
            load_a(Ab, Gh4, Gl4, txoff, bb+1, mhalf, lane);
            load_b(Bb, B4h, bb+1, khalf, rb58 + pjx);
            do_mfma(acc0, acc1, Aa, Ba, msel);
            if (it2 < 5) {
                load_a(Aa, Gh4, Gl4, txoff, bb+2, mhalf, lane);
                load_b(Ba, B4h, bb+2, khalf, rb58 + pjx);
            }
            do_mfma(acc0, acc1, Ab, Bb, msel);
        }
    } else {
        // ---- edge path (boundary rowhalf of bandq 0/13): term loop, nt=6 ----
        int ymask, tby, tbc;
        if (bandq == 0) { ymask = 1; tby = 1; tbc = (cgrp == 0) ? 5 : 6; }
        else            { ymask = 2; tby = 2; tbc = (cgrp == 0) ? 7 : 8; }
#pragma unroll 1
        for (int dq = 0; dq < 3; ++dq) {
#pragma unroll 1
            for (int kstep = 0; kstep < 4; ++kstep) {
                int kg2 = kstep*2 + khalf;
#pragma unroll
                for (int dp = 0; dp < 3; ++dp) {
                    int rc0 = rb58 + dp*58 + pjx + dq;
                    int rc1 = rc0 + 58;
                    FragH B0, B1;
                    B0.u = B4h[rc0*8 + (kg2 ^ (rc0 & 7))];
                    B1.u = B4h[rc1*8 + (kg2 ^ (rc1 & 7))];
                    for (int tm = 0; tm < 6; ++tm) {
                        int td = (tm < 2) ? 0 : (tm == 2) ? tbx : (tm < 5) ? tby : tbc;
                        const uint4* Ap = ((tm == 1) || (tm == 4)) ? Gl4 : Gh4;
                        bool masked = (tm == 2) || (tm == 5);
                        int am = (tm < 3) ? 3 : ymask;
                        FragH a;
                        a.u = Ap[(((td*9 + 3*dp + dq)*2 + mhalf)*4 + kstep)*64 + lane];
                        if (!masked) {
                            if (am & 1)
                                acc0 = __builtin_amdgcn_mfma_f32_32x32x16_f16(a.v, B0.v, acc0, 0,0,0);
                            if (am & 2)
                                acc1 = __builtin_amdgcn_mfma_f32_32x32x16_f16(a.v, B1.v, acc1, 0,0,0);
                        } else {
                            if (am & 1) {
                                FragH bm;
                                bm.u = make_uint4(B0.u.x & msel, B0.u.y & msel,
                                                  B0.u.z & msel, B0.u.w & msel);
                                acc0 = __builtin_amdgcn_mfma_f32_32x32x16_f16(a.v, bm.v, acc0, 0,0,0);
                            }
                            if (am & 2) {
                                FragH bm;
                                bm.u = make_uint4(B1.u.x & msel, B1.u.y & msel,
                                                  B1.u.z & msel, B1.u.w & msel);
                                acc1 = __builtin_amdgcn_mfma_f32_32x32x16_f16(a.v, bm.v, acc1, 0,0,0);
                            }
                        }
                    }
                }
            }
        }
    }
    // Epilogue: two 2-row chunks; at2h dead after first barrier.
    float* ot = (float*)smem;          // 112*65*4 = 29120 B
    const float* bp = b + (size_t)img*IMGSZ;
    float* up = u + (size_t)img*IMGSZ;          // in-place state update
#pragma unroll 1
    for (int ck = 0; ck < 2; ++ck) {
        __syncthreads();               // MFMA done / prev chunk reads done
        if (rowhalf == ck && pj < 56) {
#pragma unroll
            for (int r16 = 0; r16 < 16; ++r16) {
                int row = (r16 & 3) + 8*(r16 >> 2) + 4*khalf;
                int m = mhalf*32 + row;
                ot[pj*65 + m] = acc0[r16];
                ot[(56 + pj)*65 + m] = acc1[r16];
            }
        }
        __syncthreads();
        // load phase: u,b for 14 passes into registers (static indices)
        float ur[14], br[14];
#pragma unroll
        for (int p = 0; p < 14; ++p) {
            int idx = p*512 + t;
            int n = idx & 63;
            int rest = idx >> 6;                // 0..111
            int pi = (rest >= 56) ? 1 : 0;
            int j = rest - 56*pi;
            int g = ((i0o + ck*2 + pi)*OW + j)*64 + n;
            ur[p] = up[g];
            br[p] = bp[g];
        }
        // compute/store phase
#pragma unroll
        for (int p = 0; p < 14; ++p) {
            int idx = p*512 + t;
            int n = idx & 63;
            int rest = idx >> 6;
            int pi = (rest >= 56) ? 1 : 0;
            int j = rest - 56*pi;
            int iout = i0o + ck*2 + pi;
            int g = (iout*OW + j)*64 + n;
            float uo = ur[p];
            float gram = ot[(pi*56 + j)*65 + n];
            float un = uo + ETA * (br[p] - uo - gram + softthr(uo));
            if (last) {
                out[(((size_t)img*ATOMS + n)*OH + iout)*OW + j] = softthr(un);
            } else {
                up[g] = un;
                Aout[a_off(img, iout + 1, j + 1, n)] = f2h(softthr(un));
            }
        }
    }
}

extern "C" void kernel_launch(void* const* d_in, const int* in_sizes, int n_in,
                              void* d_out, int out_size, void* d_ws, size_t ws_size,
                              hipStream_t stream) {
    const float* x = (const float*)d_in[0];
    const float* D = (const float*)d_in[1];
    float* out = (float*)d_out;
    float* ws = (float*)d_ws;
    float* b  = ws;                        // NLAT f32 (channel-last)
    float* u  = b  + NLAT;                 // NLAT f32 (single buffer, in-place)
    float* DT = u  + NLAT;                 // 12288 f32
    float* Gf = DT + 12288;                // 81*4096 f32
    unsigned short* GAh = (unsigned short*)(Gf + 331776);
    unsigned short* GAl = GAh + 331776;
    unsigned short* DAh = GAl + 331776;
    unsigned short* DAl = DAh + 12288;
    unsigned short* A0  = DAl + 12288;     // 64*215552 ushorts (padded stride)
    unsigned short* A1  = A0 + (size_t)BATCH*AIMG;
    prep_a_kernel<<<1878, 256, 0, stream>>>(D, A0, DT, DAh, DAl);
    prep_gram_kernel<<<1296, 256, 0, stream>>>(DT, Gf);
    prep_packg_kernel<<<162, 256, 0, stream>>>(Gf, GAh, GAl);
    conv_b_kernel<<<BATCH*49, 256, 0, stream>>>(x, DAh, DAl, b, u, A0);
    unsigned short* ain = A0; unsigned short* aout = A1;
    for (int it = 0; it < 9; ++it) {       // iterations 2..10 (iter 1 folded)
        int last = (it == 8);
        lca_iter_kernel<<<BATCH*14, 512, 0, stream>>>(b, u, ain, aout, GAh, GAl, out, last);
        unsigned short* tmp = ain; ain = aout; aout = tmp;
    }
}

// Round 12
// 1083.693 us; speedup vs baseline: 10.3195x; 1.0960x over previous
//
#include <hip/hip_runtime.h>

#define BATCH 64
#define ATOMS 64
#define CIN 3
#define KS 8
#define H 224
#define W 224
#define OH 56
#define OW 56
#define NLAT (BATCH*ATOMS*OH*OW)   // 12,845,056
#define IMGSZ (OH*OW*ATOMS)        // 200,704 elems per image (channel-last)
#define LAM 0.1f
#define ETA 0.1f
// a-buffer: fp16, zero-padded halo, pre-swizzled: [img][R=0..57][C=0..57][64]
// element (R,C,n) at slot ((n>>3) ^ ((2R+C)&7))*8 + (n&7) within the 64.
// Per-image stride includes a 256-ushort (512 B) tail pad so the 44-chunk
// DMA overread of the last band stays in-bounds.
#define AROW 58
#define AIMG (AROW*AROW*64 + 256)  // 215,552 ushorts per image (padded)

typedef __attribute__((ext_vector_type(8)))  __bf16    bf16x8;
typedef __attribute__((ext_vector_type(8)))  _Float16  f16x8;
typedef __attribute__((ext_vector_type(16))) float     floatx16;

union FragU { uint4 u; bf16x8 v; };
union FragH { uint4 u; f16x8 v; };
union HalfBits { _Float16 h; unsigned short s; };

__device__ __forceinline__ float softthr(float u) {
    float p = u - LAM;  p = p > 0.f ? p : 0.f;
    float q = -u - LAM; q = q > 0.f ? q : 0.f;
    return p - q;
}
__device__ __forceinline__ unsigned short f2bf(float f) {   // RNE
    union { float f; unsigned int u; } c; c.f = f;
    unsigned int r = c.u + 0x7fffu + ((c.u >> 16) & 1u);
    return (unsigned short)(r >> 16);
}
__device__ __forceinline__ float bf2f(unsigned short h) {
    union { unsigned int u; float f; } c; c.u = ((unsigned int)h) << 16;
    return c.f;
}
__device__ __forceinline__ unsigned short f2h(float f) {    // fp16 bits, RNE
    HalfBits hb; hb.h = (_Float16)f; return hb.s;
}
__device__ __forceinline__ float h2f(unsigned short s) {
    HalfBits hb; hb.s = s; return (float)hb.h;
}
// swizzled ushort offset of atom n at padded coords (R,C) within an image
__device__ __forceinline__ size_t a_off(int img, int R, int C, int n) {
    return (size_t)img*AIMG + ((size_t)R*AROW + C)*64
         + ((((n >> 3) ^ ((2*R + C) & 7)) << 3) | (n & 7));
}

// Merged independent prep: blocks [0,1824) zero a-buffer halos,
// [1824,1872) build DT, [1872,1878) pack D (bf16 split).
__global__ void prep_a_kernel(const float* __restrict__ D,
                              unsigned short* __restrict__ A,
                              float* __restrict__ DT,
                              unsigned short* __restrict__ DAh,
                              unsigned short* __restrict__ DAl) {
    int bb = blockIdx.x;
    if (bb < 1824) {
        int idx = bb * 256 + threadIdx.x;   // 128 img-buf x 228 cells x 16 quads
        int ib = idx / 3648, r = idx % 3648;
        int cell = r >> 4, q = r & 15;
        int R, C;
        if      (cell < 58)  { R = 0;  C = cell; }
        else if (cell < 116) { R = 57; C = cell - 58; }
        else if (cell < 172) { R = cell - 116 + 1; C = 0; }
        else                 { R = cell - 172 + 1; C = 57; }
        size_t off = (size_t)ib*AIMG + ((size_t)R*AROW + C)*64 + q*4;
        *(ushort4*)(A + off) = make_ushort4(0, 0, 0, 0);
    } else if (bb < 1872) {
        int idx = (bb - 1824) * 256 + threadIdx.x;
        if (idx < CIN*KS*KS*ATOMS) {
            int m = idx & 63;
            int r = idx >> 6;
            int xk = r & 7, y = (r >> 3) & 7, c = r >> 6;
            DT[idx] = D[((m*CIN + c)*KS + y)*KS + xk];
        }
    } else {
        int g = (bb - 1872) * 256 + threadIdx.x;
        if (g >= 1536) return;
        int lane = g & 63;
        int r = g >> 6;
        int kstep = r % 12, mhalf = r / 12;
        int m = mhalf*32 + (lane & 31);
        int k0 = kstep*16 + (lane >> 5)*8;
#pragma unroll
        for (int j = 0; j < 8; ++j) {
            float v = D[m*192 + k0 + j];
            unsigned short h = f2bf(v);
            DAh[g*8 + j] = h;
            DAl[g*8 + j] = f2bf(v - bf2f(h));
        }
    }
}

// 9 table-sets (inclusion-exclusion for boundary classes), 9 dpq each.
__global__ void prep_gram_kernel(const float* __restrict__ DT,
                                 float* __restrict__ G) {
    int blk = blockIdx.x;              // td*16 + nchunk
    int td = blk >> 4;
    int tbl = td / 9, dpq = td % 9;
    int dp = dpq / 3, dq = dpq % 3;
    int di = 1 - dp, dj = 1 - dq;
    int ylo = (0 > -4*di) ? 0 : -4*di;
    int yhi = (8 < 8-4*di) ? 8 : 8-4*di;
    int xlo = (0 > -4*dj) ? 0 : -4*dj;
    int xhi = (8 < 8-4*dj) ? 8 : 8-4*dj;
    if (tbl==1 || tbl==5 || tbl==6) { if (yhi > 2) yhi = 2; }
    if (tbl==2 || tbl==7 || tbl==8) { if (ylo < 6) ylo = 6; }
    if (tbl==3 || tbl==5 || tbl==7) { if (xhi > 2) xhi = 2; }
    if (tbl==4 || tbl==6 || tbl==8) { if (xlo < 6) xlo = 6; }
    float sign = (tbl >= 1 && tbl <= 4) ? -1.f : 1.f;
    int t = threadIdx.x;
    int m = t & 63;
    int n = (blk & 15)*4 + (t >> 6);
    float s = 0.f;
    for (int c = 0; c < CIN; ++c)
        for (int y = ylo; y < yhi; ++y)
            for (int x = xlo; x < xhi; ++x)
                s += DT[((c*8+y)*8+x)*64 + m] *
                     DT[((c*8+y+4*di)*8 + (x+4*dj))*64 + n];
    G[td*4096 + n*64 + m] = sign * s;
}

// Pack G into MFMA A-operand layout, split FP16 hi/lo.
__global__ void prep_packg_kernel(const float* __restrict__ G,
                                  unsigned short* __restrict__ GAh,
                                  unsigned short* __restrict__ GAl) {
    int g = blockIdx.x * 256 + threadIdx.x;      // 162*256 = 41472 groups
    int lane = g & 63;
    int r = g >> 6;
    int kstep = r & 3; r >>= 2;
    int mhalf = r & 1; int td = r >> 1;          // tbl*9+dpq
    int m = mhalf*32 + (lane & 31);
    int n = kstep*16 + (lane >> 5)*8;
    const float* src = G + td*4096 + n*64 + m;
#pragma unroll
    for (int j = 0; j < 8; ++j) {
        float v = src[j*64];
        unsigned short h = f2h(v);
        GAh[g*8 + j] = h;
        GAl[g*8 + j] = f2h(v - h2f(h));
    }
}

// b = conv2d(x, D, stride4, pad2); u = 0.1*b; a1 = softthr(u) -> A0 (swizzled).
// Output CHANNEL-LAST [i][j][n].
__global__ __launch_bounds__(256) void conv_b_kernel(
        const float* __restrict__ x,
        const unsigned short* __restrict__ DAh,
        const unsigned short* __restrict__ DAl,
        float* __restrict__ b, float* __restrict__ u,
        unsigned short* __restrict__ A0) {
    __shared__ __align__(16) unsigned short xth[CIN*36*36];
    __shared__ __align__(16) unsigned short xtl[CIN*36*36];
    __shared__ float ot[64*65];
    int blk = blockIdx.x;
    int img = blk / 49, tile = blk % 49;
    int i0 = (tile / 7) * 8, j0 = (tile % 7) * 8;
    int t = threadIdx.x;
    int r0 = 4*i0 - 2, c0 = 4*j0 - 2;
    for (int f = t; f < CIN*36*36; f += 256) {
        int cc = f / 1296, rem = f % 1296;
        int rr = rem / 36, qq = rem % 36;
        int Y = r0 + rr, X = c0 + qq;
        float v = 0.f;
        if (Y >= 0 && Y < H && X >= 0 && X < W)
            v = x[((img*CIN + cc)*H + Y)*W + X];
        unsigned short h = f2bf(v);
        xth[f] = h;
        xtl[f] = f2bf(v - bf2f(h));
    }
    __syncthreads();
    int lane = t & 63, wave = t >> 6;
    int mhalf = wave & 1, poshalf = wave >> 1;
    int pos = poshalf*32 + (lane & 31), pi = pos >> 3, pj = pos & 7;
    int khalf = lane >> 5;
    floatx16 acc;
#pragma unroll
    for (int i = 0; i < 16; ++i) acc[i] = 0.f;
    const uint4* Ah4 = (const uint4*)DAh;
    const uint4* Al4 = (const uint4*)DAl;
#pragma unroll 3
    for (int kstep = 0; kstep < 12; ++kstep) {
        int k0 = kstep*16 + khalf*8;
        int cc = k0 >> 6, yy = (k0 >> 3) & 7;
        int boff = cc*1296 + (4*pi + yy)*36 + 4*pj;
        FragU ah, al, bh, bl;
        ah.u = Ah4[(mhalf*12 + kstep)*64 + lane];
        al.u = Al4[(mhalf*12 + kstep)*64 + lane];
        const uint2* ph = (const uint2*)(xth + boff);
        uint2 h0 = ph[0], h1 = ph[1];
        bh.u = make_uint4(h0.x, h0.y, h1.x, h1.y);
        const uint2* pl = (const uint2*)(xtl + boff);
        uint2 l0 = pl[0], l1 = pl[1];
        bl.u = make_uint4(l0.x, l0.y, l1.x, l1.y);
        acc = __builtin_amdgcn_mfma_f32_32x32x16_bf16(ah.v, bh.v, acc, 0, 0, 0);
        acc = __builtin_amdgcn_mfma_f32_32x32x16_bf16(ah.v, bl.v, acc, 0, 0, 0);
        acc = __builtin_amdgcn_mfma_f32_32x32x16_bf16(al.v, bh.v, acc, 0, 0, 0);
    }
#pragma unroll
    for (int r16 = 0; r16 < 16; ++r16) {
        int row = (r16 & 3) + 8*(r16 >> 2) + 4*khalf;
        ot[(mhalf*32 + row)*65 + pos] = acc[r16];
    }
    __syncthreads();
    // channel-last epilogue: lane = channel -> 256B contiguous stores
    int m = t & 63;
    float* bp = b + (size_t)img*IMGSZ;
    float* up = u + (size_t)img*IMGSZ;
#pragma unroll
    for (int e = 0; e < 16; ++e) {
        int pp = e*4 + (t >> 6);
        int gi = i0 + (pp >> 3), gj = j0 + (pp & 7);
        int gidx = (gi*OW + gj)*64 + m;
        float v = ot[m*65 + pp];
        bp[gidx] = v;
        float uv = ETA * v;
        up[gidx] = uv;
        A0[a_off(img, gi + 1, gj + 1, m)] = f2h(softthr(uv));
    }
}

// ---- MFMA helpers ----
__device__ __forceinline__ void load_a(uint4 (&A)[9], const uint4* __restrict__ Gh4,
                                       const uint4* __restrict__ Gl4,
                                       int txoff, int bb, int mhalf, int lane) {
    int dq = bb >> 2, ks = bb & 3;
#pragma unroll
    for (int dp = 0; dp < 3; ++dp) {
        int abase = (((3*dp + dq)*2 + mhalf)*4 + ks)*64 + lane;
        A[dp*3+0] = Gh4[abase];
        A[dp*3+1] = Gl4[abase];
        A[dp*3+2] = Gh4[txoff + abase];
    }
}
// 6 B-fragment slots (rows i0o..i0o+5 of the staged band) for one body.
__device__ __forceinline__ void load_b6(uint4 (&B)[6], const uint4* __restrict__ B4h,
                                        int bb, int khalf, int pjx) {
    int dq = bb >> 2, ks = bb & 3;
    int kg2 = ks*2 + khalf;
#pragma unroll
    for (int p = 0; p < 6; ++p) {
        int rc = p*58 + pjx + dq;
        B[p] = B4h[rc*8 + (kg2 ^ (rc & 7))];
    }
}
// Two row-pairs sharing the same A fragments: pair0 = rows (i0o, i0o+1)
// using slots dp, dp+1; pair1 = rows (i0o+2, i0o+3) using slots dp+2, dp+3.
__device__ __forceinline__ void do_mfma2(floatx16& a00, floatx16& a01,
                                         floatx16& a10, floatx16& a11,
                                         const uint4 (&A)[9], const uint4 (&B)[6],
                                         unsigned msel) {
    __builtin_amdgcn_s_setprio(1);
#pragma unroll
    for (int dp = 0; dp < 3; ++dp) {
        FragH a0, a1, ax;
        a0.u = A[dp*3+0]; a1.u = A[dp*3+1]; ax.u = A[dp*3+2];
        FragH b0, b1, bm0, bm1;
        b0.u = B[dp]; b1.u = B[dp+1];
        bm0.u = make_uint4(b0.u.x & msel, b0.u.y & msel,
                           b0.u.z & msel, b0.u.w & msel);
        bm1.u = make_uint4(b1.u.x & msel, b1.u.y & msel,
                           b1.u.z & msel, b1.u.w & msel);
        a00 = __builtin_amdgcn_mfma_f32_32x32x16_f16(a0.v, b0.v, a00, 0,0,0);
        a01 = __builtin_amdgcn_mfma_f32_32x32x16_f16(a0.v, b1.v, a01, 0,0,0);
        a00 = __builtin_amdgcn_mfma_f32_32x32x16_f16(a1.v, b0.v, a00, 0,0,0);
        a01 = __builtin_amdgcn_mfma_f32_32x32x16_f16(a1.v, b1.v, a01, 0,0,0);
        a00 = __builtin_amdgcn_mfma_f32_32x32x16_f16(ax.v, bm0.v, a00, 0,0,0);
        a01 = __builtin_amdgcn_mfma_f32_32x32x16_f16(ax.v, bm1.v, a01, 0,0,0);
        FragH c0, c1, cm0, cm1;
        c0.u = B[dp+2]; c1.u = B[dp+3];
        cm0.u = make_uint4(c0.u.x & msel, c0.u.y & msel,
                           c0.u.z & msel, c0.u.w & msel);
        cm1.u = make_uint4(c1.u.x & msel, c1.u.y & msel,
                           c1.u.z & msel, c1.u.w & msel);
        a10 = __builtin_amdgcn_mfma_f32_32x32x16_f16(a0.v, c0.v, a10, 0,0,0);
        a11 = __builtin_amdgcn_mfma_f32_32x32x16_f16(a0.v, c1.v, a11, 0,0,0);
        a10 = __builtin_amdgcn_mfma_f32_32x32x16_f16(a1.v, c0.v, a10, 0,0,0);
        a11 = __builtin_amdgcn_mfma_f32_32x32x16_f16(a1.v, c1.v, a11, 0,0,0);
        a10 = __builtin_amdgcn_mfma_f32_32x32x16_f16(ax.v, cm0.v, a10, 0,0,0);
        a11 = __builtin_amdgcn_mfma_f32_32x32x16_f16(ax.v, cm1.v, a11, 0,0,0);
    }
    __builtin_amdgcn_s_setprio(0);
}
// Runtime term-loop for one row-pair with boundary params; ym=0 -> interior.
__device__ __forceinline__ void edge_pair(floatx16& a0r, floatx16& a1r,
        const uint4* __restrict__ B4h, const uint4* __restrict__ Gh4,
        const uint4* __restrict__ Gl4, int slot0, int pjx,
        int mhalf, int khalf, int lane, int tbx, unsigned msel,
        int ym, int tby, int tbc) {
#pragma unroll 1
    for (int dq = 0; dq < 3; ++dq) {
#pragma unroll 1
        for (int kstep = 0; kstep < 4; ++kstep) {
            int kg2 = kstep*2 + khalf;
#pragma unroll
            for (int dp = 0; dp < 3; ++dp) {
                int rc0 = (slot0 + dp)*58 + pjx + dq;
                int rc1 = rc0 + 58;
                FragH B0, B1;
                B0.u = B4h[rc0*8 + (kg2 ^ (rc0 & 7))];
                B1.u = B4h[rc1*8 + (kg2 ^ (rc1 & 7))];
                for (int tm = 0; tm < 6; ++tm) {
                    int td = (tm < 2) ? 0 : (tm == 2) ? tbx : (tm < 5) ? tby : tbc;
                    const uint4* Ap = ((tm == 1) || (tm == 4)) ? Gl4 : Gh4;
                    bool masked = (tm == 2) || (tm == 5);
                    int am = (tm < 3) ? 3 : ym;
                    FragH a;
                    a.u = Ap[(((td*9 + 3*dp + dq)*2 + mhalf)*4 + kstep)*64 + lane];
                    if (!masked) {
                        if (am & 1)
                            a0r = __builtin_amdgcn_mfma_f32_32x32x16_f16(a.v, B0.v, a0r, 0,0,0);
                        if (am & 2)
                            a1r = __builtin_amdgcn_mfma_f32_32x32x16_f16(a.v, B1.v, a1r, 0,0,0);
                    } else {
                        if (am & 1) {
                            FragH bm;
                            bm.u = make_uint4(B0.u.x & msel, B0.u.y & msel,
                                              B0.u.z & msel, B0.u.w & msel);
                            a0r = __builtin_amdgcn_mfma_f32_32x32x16_f16(a.v, bm.v, a0r, 0,0,0);
                        }
                        if (am & 2) {
                            FragH bm;
                            bm.u = make_uint4(B1.u.x & msel, B1.u.y & msel,
                                              B1.u.z & msel, B1.u.w & msel);
                            a1r = __builtin_amdgcn_mfma_f32_32x32x16_f16(a.v, bm.v, a1r, 0,0,0);
                        }
                    }
                }
            }
        }
    }
}

// One LCA step on a 4-row x 56-col band, 256 threads = 4 waves {mhalf, cgrp}.
// R15: A-fragment sharing — each wave holds 4 accumulators (both row-pairs)
// and reuses each A-fragment for 12 MFMAs (vs 6): per-block Gram A-load
// traffic halves and per-wave MFMA density doubles (R7's do_mfma2, verified).
__global__ __launch_bounds__(256, 2) void lca_iter_kernel(
        const float* __restrict__ b, float* __restrict__ u,
        const unsigned short* __restrict__ Ain,
        unsigned short* __restrict__ Aout,
        const unsigned short* __restrict__ GAh,
        const unsigned short* __restrict__ GAl,
        float* __restrict__ out, int last) {
    __shared__ __align__(1024) unsigned char smem[45056];  // 44 KB stage / 29120 ot
    unsigned short* at2h = (unsigned short*)smem;          // [rc][swizzled n]
    int blk = blockIdx.x;
    int img = blk / 14, bandq = blk % 14;
    int i0o = bandq*4;                 // first output row of the band
    int t = threadIdx.x;
    // Phase 1: padded rows R = 4*bandq .. +5 (6 rows x 58 x 64 fp16) -> LDS.
    {
        const char* gbase = (const char*)(Ain + (size_t)img*AIMG
                              + (size_t)i0o*AROW*64) + (t & 63)*16;
        char* lbase = (char*)smem;
        int w = t >> 6;
        for (int c = w; c < 44; c += 4) {
            __builtin_amdgcn_global_load_lds(
                (const __attribute__((address_space(1))) unsigned int*)(gbase + c*1024),
                (__attribute__((address_space(3))) unsigned int*)(lbase + c*1024),
                16, 0, 0);
        }
    }
    __syncthreads();
    int lane = t & 63, wave = t >> 6;
    int mhalf = wave & 1, cgrp = wave >> 1;
    int khalf = lane >> 5, cl = lane & 31;
    int pj = cgrp*32 + cl;
    int pjx = (pj < 56) ? pj : 0;                // clamp invalid columns
    floatx16 a00, a01, a10, a11;
#pragma unroll
    for (int i = 0; i < 16; ++i) { a00[i]=0.f; a01[i]=0.f; a10[i]=0.f; a11[i]=0.f; }
    const uint4* Gh4 = (const uint4*)GAh;
    const uint4* Gl4 = (const uint4*)GAl;
    const uint4* B4h = (const uint4*)at2h;
    int tbx = (cgrp == 0) ? 3 : 4;               // X boundary table
    int txoff = (tbx*9)*512;
    unsigned msel = (cl == ((cgrp == 0) ? 0 : 23)) ? 0xFFFFFFFFu : 0u;
    bool edge = (bandq == 0) || (bandq == 13);
    if (!edge) {
        // ---- interior: A double-buffered, B single-buffered, 12 bodies ----
        uint4 Aa[9], Ab[9], B[6];
        load_a(Aa, Gh4, Gl4, txoff, 0, mhalf, lane);
#pragma unroll 1
        for (int it2 = 0; it2 < 6; ++it2) {
            int bb = it2*2;
            load_a(Ab, Gh4, Gl4, txoff, bb+1, mhalf, lane);
            load_b6(B, B4h, bb, khalf, pjx);
            do_mfma2(a00, a01, a10, a11, Aa, B, msel);
            if (it2 < 5) {
                load_a(Aa, Gh4, Gl4, txoff, bb+2, mhalf, lane);
            }
            load_b6(B, B4h, bb+1, khalf, pjx);
            do_mfma2(a00, a01, a10, a11, Ab, B, msel);
        }
    } else {
        // ---- edge (bandq 0/13): runtime term loop per pair; ym=0 pair is
        //      interior-only terms (verified structure from R7) ----
        int tby, tbc, ym0, ym1;
        if (bandq == 0) { tby = 1; tbc = (cgrp == 0) ? 5 : 6; ym0 = 1; ym1 = 0; }
        else            { tby = 2; tbc = (cgrp == 0) ? 7 : 8; ym0 = 0; ym1 = 2; }
        edge_pair(a00, a01, B4h, Gh4, Gl4, 0, pjx, mhalf, khalf, lane,
                  tbx, msel, ym0, tby, tbc);
        edge_pair(a10, a11, B4h, Gh4, Gl4, 2, pjx, mhalf, khalf, lane,
                  tbx, msel, ym1, tby, tbc);
    }
    // Epilogue: two 2-row chunks; at2h dead after first barrier.
    float* ot = (float*)smem;          // 112*65*4 = 29120 B
    const float* bp = b + (size_t)img*IMGSZ;
    float* up = u + (size_t)img*IMGSZ;          // in-place state update
#pragma unroll
    for (int ck = 0; ck < 2; ++ck) {
        __syncthreads();               // MFMA done / prev chunk reads done
        const floatx16& eA = (ck == 0) ? a00 : a10;
        const floatx16& eB = (ck == 0) ? a01 : a11;
        if (pj < 56) {
#pragma unroll
            for (int r16 = 0; r16 < 16; ++r16) {
                int row = (r16 & 3) + 8*(r16 >> 2) + 4*khalf;
                int m = mhalf*32 + row;
                ot[pj*65 + m] = eA[r16];
                ot[(56 + pj)*65 + m] = eB[r16];
            }
        }
        __syncthreads();
#pragma unroll
        for (int half = 0; half < 2; ++half) {
            // load phase: u,b for 14 passes into registers (static indices)
            float ur[14], br[14];
#pragma unroll
            for (int p = 0; p < 14; ++p) {
                int idx = (half*14 + p)*256 + t;
                int n = idx & 63;
                int rest = idx >> 6;                // 0..111
                int pi = (rest >= 56) ? 1 : 0;
                int j = rest - 56*pi;
                int g = ((i0o + ck*2 + pi)*OW + j)*64 + n;
                ur[p] = up[g];
                br[p] = bp[g];
            }
            // compute/store phase
#pragma unroll
            for (int p = 0; p < 14; ++p) {
                int idx = (half*14 + p)*256 + t;
                int n = idx & 63;
                int rest = idx >> 6;
                int pi = (rest >= 56) ? 1 : 0;
                int j = rest - 56*pi;
                int iout = i0o + ck*2 + pi;
                int g = (iout*OW + j)*64 + n;
                float uo = ur[p];
                float gram = ot[(pi*56 + j)*65 + n];
                float un = uo + ETA * (br[p] - uo - gram + softthr(uo));
                if (last) {
                    out[(((size_t)img*ATOMS + n)*OH + iout)*OW + j] = softthr(un);
                } else {
                    up[g] = un;
                    Aout[a_off(img, iout + 1, j + 1, n)] = f2h(softthr(un));
                }
            }
        }
    }
}

extern "C" void kernel_launch(void* const* d_in, const int* in_sizes, int n_in,
                              void* d_out, int out_size, void* d_ws, size_t ws_size,
                              hipStream_t stream) {
    const float* x = (const float*)d_in[0];
    const float* D = (const float*)d_in[1];
    float* out = (float*)d_out;
    float* ws = (float*)d_ws;
    float* b  = ws;                        // NLAT f32 (channel-last)
    float* u  = b  + NLAT;                 // NLAT f32 (single buffer, in-place)
    float* DT = u  + NLAT;                 // 12288 f32
    float* Gf = DT + 12288;                // 81*4096 f32
    unsigned short* GAh = (unsigned short*)(Gf + 331776);
    unsigned short* GAl = GAh + 331776;
    unsigned short* DAh = GAl + 331776;
    unsigned short* DAl = DAh + 12288;
    unsigned short* A0  = DAl + 12288;     // 64*215552 ushorts (padded stride)
    unsigned short* A1  = A0 + (size_t)BATCH*AIMG;
    prep_a_kernel<<<1878, 256, 0, stream>>>(D, A0, DT, DAh, DAl);
    prep_gram_kernel<<<1296, 256, 0, stream>>>(DT, Gf);
    prep_packg_kernel<<<162, 256, 0, stream>>>(Gf, GAh, GAl);
    conv_b_kernel<<<BATCH*49, 256, 0, stream>>>(x, DAh, DAl, b, u, A0);
    unsigned short* ain = A0; unsigned short* aout = A1;
    for (int it = 0; it < 9; ++it) {       // iterations 2..10 (iter 1 folded)
        int last = (it == 8);
        lca_iter_kernel<<<BATCH*14, 256, 0, stream>>>(b, u, ain, aout, GAh, GAl, out, last);
        unsigned short* tmp = ain; ain = aout; aout = tmp;
    }
}

// Round 14
// 972.954 us; speedup vs baseline: 11.4941x; 1.1138x over previous
//
#include <hip/hip_runtime.h>

#define BATCH 64
#define ATOMS 64
#define CIN 3
#define KS 8
#define H 224
#define W 224
#define OH 56
#define OW 56
#define NLAT (BATCH*ATOMS*OH*OW)   // 12,845,056
#define IMGSZ (OH*OW*ATOMS)        // 200,704 elems per image (channel-last)
#define LAM 0.1f
#define ETA 0.1f
// a-buffer: fp16, zero-padded halo, pre-swizzled: [img][R=0..57][C=0..57][64]
// element (R,C,n) at slot ((n>>3) ^ ((2R+C)&7))*8 + (n&7) within the 64.
// Per-image stride includes a 256-ushort (512 B) tail pad so the 44-chunk
// DMA overread of the last band stays in-bounds.
#define AROW 58
#define AIMG (AROW*AROW*64 + 256)  // 215,552 ushorts per image (padded)

typedef __attribute__((ext_vector_type(8)))  __bf16    bf16x8;
typedef __attribute__((ext_vector_type(8)))  _Float16  f16x8;
typedef __attribute__((ext_vector_type(16))) float     floatx16;

union FragU { uint4 u; bf16x8 v; };
union FragH { uint4 u; f16x8 v; };
union HalfBits { _Float16 h; unsigned short s; };

__device__ __forceinline__ float softthr(float u) {
    float p = u - LAM;  p = p > 0.f ? p : 0.f;
    float q = -u - LAM; q = q > 0.f ? q : 0.f;
    return p - q;
}
__device__ __forceinline__ unsigned short f2bf(float f) {   // RNE
    union { float f; unsigned int u; } c; c.f = f;
    unsigned int r = c.u + 0x7fffu + ((c.u >> 16) & 1u);
    return (unsigned short)(r >> 16);
}
__device__ __forceinline__ float bf2f(unsigned short h) {
    union { unsigned int u; float f; } c; c.u = ((unsigned int)h) << 16;
    return c.f;
}
__device__ __forceinline__ unsigned short f2h(float f) {    // fp16 bits, RNE
    HalfBits hb; hb.h = (_Float16)f; return hb.s;
}
__device__ __forceinline__ float h2f(unsigned short s) {
    HalfBits hb; hb.s = s; return (float)hb.h;
}
// swizzled ushort offset of atom n at padded coords (R,C) within an image
__device__ __forceinline__ size_t a_off(int img, int R, int C, int n) {
    return (size_t)img*AIMG + ((size_t)R*AROW + C)*64
         + ((((n >> 3) ^ ((2*R + C) & 7)) << 3) | (n & 7));
}

// Merged independent prep: blocks [0,1824) zero a-buffer halos,
// [1824,1872) build DT, [1872,1878) pack D (bf16 split).
__global__ void prep_a_kernel(const float* __restrict__ D,
                              unsigned short* __restrict__ A,
                              float* __restrict__ DT,
                              unsigned short* __restrict__ DAh,
                              unsigned short* __restrict__ DAl) {
    int bb = blockIdx.x;
    if (bb < 1824) {
        int idx = bb * 256 + threadIdx.x;   // 128 img-buf x 228 cells x 16 quads
        int ib = idx / 3648, r = idx % 3648;
        int cell = r >> 4, q = r & 15;
        int R, C;
        if      (cell < 58)  { R = 0;  C = cell; }
        else if (cell < 116) { R = 57; C = cell - 58; }
        else if (cell < 172) { R = cell - 116 + 1; C = 0; }
        else                 { R = cell - 172 + 1; C = 57; }
        size_t off = (size_t)ib*AIMG + ((size_t)R*AROW + C)*64 + q*4;
        *(ushort4*)(A + off) = make_ushort4(0, 0, 0, 0);
    } else if (bb < 1872) {
        int idx = (bb - 1824) * 256 + threadIdx.x;
        if (idx < CIN*KS*KS*ATOMS) {
            int m = idx & 63;
            int r = idx >> 6;
            int xk = r & 7, y = (r >> 3) & 7, c = r >> 6;
            DT[idx] = D[((m*CIN + c)*KS + y)*KS + xk];
        }
    } else {
        int g = (bb - 1872) * 256 + threadIdx.x;
        if (g >= 1536) return;
        int lane = g & 63;
        int r = g >> 6;
        int kstep = r % 12, mhalf = r / 12;
        int m = mhalf*32 + (lane & 31);
        int k0 = kstep*16 + (lane >> 5)*8;
#pragma unroll
        for (int j = 0; j < 8; ++j) {
            float v = D[m*192 + k0 + j];
            unsigned short h = f2bf(v);
            DAh[g*8 + j] = h;
            DAl[g*8 + j] = f2bf(v - bf2f(h));
        }
    }
}

// 9 table-sets (inclusion-exclusion for boundary classes), 9 dpq each.
__global__ void prep_gram_kernel(const float* __restrict__ DT,
                                 float* __restrict__ G) {
    int blk = blockIdx.x;              // td*16 + nchunk
    int td = blk >> 4;
    int tbl = td / 9, dpq = td % 9;
    int dp = dpq / 3, dq = dpq % 3;
    int di = 1 - dp, dj = 1 - dq;
    int ylo = (0 > -4*di) ? 0 : -4*di;
    int yhi = (8 < 8-4*di) ? 8 : 8-4*di;
    int xlo = (0 > -4*dj) ? 0 : -4*dj;
    int xhi = (8 < 8-4*dj) ? 8 : 8-4*dj;
    if (tbl==1 || tbl==5 || tbl==6) { if (yhi > 2) yhi = 2; }
    if (tbl==2 || tbl==7 || tbl==8) { if (ylo < 6) ylo = 6; }
    if (tbl==3 || tbl==5 || tbl==7) { if (xhi > 2) xhi = 2; }
    if (tbl==4 || tbl==6 || tbl==8) { if (xlo < 6) xlo = 6; }
    float sign = (tbl >= 1 && tbl <= 4) ? -1.f : 1.f;
    int t = threadIdx.x;
    int m = t & 63;
    int n = (blk & 15)*4 + (t >> 6);
    float s = 0.f;
    for (int c = 0; c < CIN; ++c)
        for (int y = ylo; y < yhi; ++y)
            for (int x = xlo; x < xhi; ++x)
                s += DT[((c*8+y)*8+x)*64 + m] *
                     DT[((c*8+y+4*di)*8 + (x+4*dj))*64 + n];
    G[td*4096 + n*64 + m] = sign * s;
}

// Pack G into MFMA A-operand layout, split FP16 hi/lo.
__global__ void prep_packg_kernel(const float* __restrict__ G,
                                  unsigned short* __restrict__ GAh,
                                  unsigned short* __restrict__ GAl) {
    int g = blockIdx.x * 256 + threadIdx.x;      // 162*256 = 41472 groups
    int lane = g & 63;
    int r = g >> 6;
    int kstep = r & 3; r >>= 2;
    int mhalf = r & 1; int td = r >> 1;          // tbl*9+dpq
    int m = mhalf*32 + (lane & 31);
    int n = kstep*16 + (lane >> 5)*8;
    const float* src = G + td*4096 + n*64 + m;
#pragma unroll
    for (int j = 0; j < 8; ++j) {
        float v = src[j*64];
        unsigned short h = f2h(v);
        GAh[g*8 + j] = h;
        GAl[g*8 + j] = f2h(v - h2f(h));
    }
}

// b = conv2d(x, D, stride4, pad2); u = 0.1*b; a1 = softthr(u) -> A0 (swizzled).
// Output CHANNEL-LAST [i][j][n].
__global__ __launch_bounds__(256) void conv_b_kernel(
        const float* __restrict__ x,
        const unsigned short* __restrict__ DAh,
        const unsigned short* __restrict__ DAl,
        float* __restrict__ b, float* __restrict__ u,
        unsigned short* __restrict__ A0) {
    __shared__ __align__(16) unsigned short xth[CIN*36*36];
    __shared__ __align__(16) unsigned short xtl[CIN*36*36];
    __shared__ float ot[64*65];
    int blk = blockIdx.x;
    int img = blk / 49, tile = blk % 49;
    int i0 = (tile / 7) * 8, j0 = (tile % 7) * 8;
    int t = threadIdx.x;
    int r0 = 4*i0 - 2, c0 = 4*j0 - 2;
    for (int f = t; f < CIN*36*36; f += 256) {
        int cc = f / 1296, rem = f % 1296;
        int rr = rem / 36, qq = rem % 36;
        int Y = r0 + rr, X = c0 + qq;
        float v = 0.f;
        if (Y >= 0 && Y < H && X >= 0 && X < W)
            v = x[((img*CIN + cc)*H + Y)*W + X];
        unsigned short h = f2bf(v);
        xth[f] = h;
        xtl[f] = f2bf(v - bf2f(h));
    }
    __syncthreads();
    int lane = t & 63, wave = t >> 6;
    int mhalf = wave & 1, poshalf = wave >> 1;
    int pos = poshalf*32 + (lane & 31), pi = pos >> 3, pj = pos & 7;
    int khalf = lane >> 5;
    floatx16 acc;
#pragma unroll
    for (int i = 0; i < 16; ++i) acc[i] = 0.f;
    const uint4* Ah4 = (const uint4*)DAh;
    const uint4* Al4 = (const uint4*)DAl;
#pragma unroll 3
    for (int kstep = 0; kstep < 12; ++kstep) {
        int k0 = kstep*16 + khalf*8;
        int cc = k0 >> 6, yy = (k0 >> 3) & 7;
        int boff = cc*1296 + (4*pi + yy)*36 + 4*pj;
        FragU ah, al, bh, bl;
        ah.u = Ah4[(mhalf*12 + kstep)*64 + lane];
        al.u = Al4[(mhalf*12 + kstep)*64 + lane];
        const uint2* ph = (const uint2*)(xth + boff);
        uint2 h0 = ph[0], h1 = ph[1];
        bh.u = make_uint4(h0.x, h0.y, h1.x, h1.y);
        const uint2* pl = (const uint2*)(xtl + boff);
        uint2 l0 = pl[0], l1 = pl[1];
        bl.u = make_uint4(l0.x, l0.y, l1.x, l1.y);
        acc = __builtin_amdgcn_mfma_f32_32x32x16_bf16(ah.v, bh.v, acc, 0, 0, 0);
        acc = __builtin_amdgcn_mfma_f32_32x32x16_bf16(ah.v, bl.v, acc, 0, 0, 0);
        acc = __builtin_amdgcn_mfma_f32_32x32x16_bf16(al.v, bh.v, acc, 0, 0, 0);
    }
#pragma unroll
    for (int r16 = 0; r16 < 16; ++r16) {
        int row = (r16 & 3) + 8*(r16 >> 2) + 4*khalf;
        ot[(mhalf*32 + row)*65 + pos] = acc[r16];
    }
    __syncthreads();
    // channel-last epilogue: lane = channel -> 256B contiguous stores
    int m = t & 63;
    float* bp = b + (size_t)img*IMGSZ;
    float* up = u + (size_t)img*IMGSZ;
#pragma unroll
    for (int e = 0; e < 16; ++e) {
        int pp = e*4 + (t >> 6);
        int gi = i0 + (pp >> 3), gj = j0 + (pp & 7);
        int gidx = (gi*OW + gj)*64 + m;
        float v = ot[m*65 + pp];
        bp[gidx] = v;
        float uv = ETA * v;
        up[gidx] = uv;
        A0[a_off(img, gi + 1, gj + 1, m)] = f2h(softthr(uv));
    }
}

// ---- MFMA helpers ----
__device__ __forceinline__ void load_a(uint4 (&A)[9], const uint4* __restrict__ Gh4,
                                       const uint4* __restrict__ Gl4,
                                       int txoff, int bb, int mhalf, int lane) {
    int dq = bb >> 2, ks = bb & 3;
#pragma unroll
    for (int dp = 0; dp < 3; ++dp) {
        int abase = (((3*dp + dq)*2 + mhalf)*4 + ks)*64 + lane;
        A[dp*3+0] = Gh4[abase];
        A[dp*3+1] = Gl4[abase];
        A[dp*3+2] = Gh4[txoff + abase];
    }
}
// 6 B-fragment slots (rows i0o..i0o+5 of the staged band) for one body.
__device__ __forceinline__ void load_b6(uint4 (&B)[6], const uint4* __restrict__ B4h,
                                        int bb, int khalf, int pjx) {
    int dq = bb >> 2, ks = bb & 3;
    int kg2 = ks*2 + khalf;
#pragma unroll
    for (int p = 0; p < 6; ++p) {
        int rc = p*58 + pjx + dq;
        B[p] = B4h[rc*8 + (kg2 ^ (rc & 7))];
    }
}
// Two row-pairs sharing the same A fragments: pair0 = rows (i0o, i0o+1)
// using slots dp, dp+1; pair1 = rows (i0o+2, i0o+3) using slots dp+2, dp+3.
__device__ __forceinline__ void do_mfma2(floatx16& a00, floatx16& a01,
                                         floatx16& a10, floatx16& a11,
                                         const uint4 (&A)[9], const uint4 (&B)[6],
                                         unsigned msel) {
    __builtin_amdgcn_s_setprio(1);
#pragma unroll
    for (int dp = 0; dp < 3; ++dp) {
        FragH a0, a1, ax;
        a0.u = A[dp*3+0]; a1.u = A[dp*3+1]; ax.u = A[dp*3+2];
        FragH b0, b1, bm0, bm1;
        b0.u = B[dp]; b1.u = B[dp+1];
        bm0.u = make_uint4(b0.u.x & msel, b0.u.y & msel,
                           b0.u.z & msel, b0.u.w & msel);
        bm1.u = make_uint4(b1.u.x & msel, b1.u.y & msel,
                           b1.u.z & msel, b1.u.w & msel);
        a00 = __builtin_amdgcn_mfma_f32_32x32x16_f16(a0.v, b0.v, a00, 0,0,0);
        a01 = __builtin_amdgcn_mfma_f32_32x32x16_f16(a0.v, b1.v, a01, 0,0,0);
        a00 = __builtin_amdgcn_mfma_f32_32x32x16_f16(a1.v, b0.v, a00, 0,0,0);
        a01 = __builtin_amdgcn_mfma_f32_32x32x16_f16(a1.v, b1.v, a01, 0,0,0);
        a00 = __builtin_amdgcn_mfma_f32_32x32x16_f16(ax.v, bm0.v, a00, 0,0,0);
        a01 = __builtin_amdgcn_mfma_f32_32x32x16_f16(ax.v, bm1.v, a01, 0,0,0);
        FragH c0, c1, cm0, cm1;
        c0.u = B[dp+2]; c1.u = B[dp+3];
        cm0.u = make_uint4(c0.u.x & msel, c0.u.y & msel,
                           c0.u.z & msel, c0.u.w & msel);
        cm1.u = make_uint4(c1.u.x & msel, c1.u.y & msel,
                           c1.u.z & msel, c1.u.w & msel);
        a10 = __builtin_amdgcn_mfma_f32_32x32x16_f16(a0.v, c0.v, a10, 0,0,0);
        a11 = __builtin_amdgcn_mfma_f32_32x32x16_f16(a0.v, c1.v, a11, 0,0,0);
        a10 = __builtin_amdgcn_mfma_f32_32x32x16_f16(a1.v, c0.v, a10, 0,0,0);
        a11 = __builtin_amdgcn_mfma_f32_32x32x16_f16(a1.v, c1.v, a11, 0,0,0);
        a10 = __builtin_amdgcn_mfma_f32_32x32x16_f16(ax.v, cm0.v, a10, 0,0,0);
        a11 = __builtin_amdgcn_mfma_f32_32x32x16_f16(ax.v, cm1.v, a11, 0,0,0);
    }
    __builtin_amdgcn_s_setprio(0);
}
// Y-boundary correction for ONE output row (the image-edge row): applies
// tby (hi+lo) and tbc (masked) terms on top of the interior result.
// Valid because staged halo rows are zero, so the interior path's T0/tbx
// application over them contributes nothing.
__device__ __forceinline__ void edge_corr(floatx16& tgt,
        const uint4* __restrict__ B4h, const uint4* __restrict__ Gh4,
        const uint4* __restrict__ Gl4, int slotbase, int pjx,
        int mhalf, int khalf, int lane, unsigned msel, int tby, int tbc) {
#pragma unroll 1
    for (int dq = 0; dq < 3; ++dq) {
#pragma unroll 1
        for (int ks = 0; ks < 4; ++ks) {
            int kg2 = ks*2 + khalf;
#pragma unroll
            for (int dp = 0; dp < 3; ++dp) {
                int rc = (slotbase + dp)*58 + pjx + dq;
                FragH B0, bm, ah, al, ac;
                B0.u = B4h[rc*8 + (kg2 ^ (rc & 7))];
                int ab = (((tby*9 + 3*dp + dq)*2 + mhalf)*4 + ks)*64 + lane;
                int cb = (((tbc*9 + 3*dp + dq)*2 + mhalf)*4 + ks)*64 + lane;
                ah.u = Gh4[ab];
                al.u = Gl4[ab];
                ac.u = Gh4[cb];
                bm.u = make_uint4(B0.u.x & msel, B0.u.y & msel,
                                  B0.u.z & msel, B0.u.w & msel);
                tgt = __builtin_amdgcn_mfma_f32_32x32x16_f16(ah.v, B0.v, tgt, 0,0,0);
                tgt = __builtin_amdgcn_mfma_f32_32x32x16_f16(al.v, B0.v, tgt, 0,0,0);
                tgt = __builtin_amdgcn_mfma_f32_32x32x16_f16(ac.v, bm.v, tgt, 0,0,0);
            }
        }
    }
}

// One LCA step on a 4-row x 56-col band, 256 threads = 4 waves {mhalf, cgrp}.
// R16 = R15 + uniform main path: ALL blocks (incl. edge bands) run the
// pipelined A-shared interior loop (halo rows are zero so T0/tbx over them
// is exact); edge bands append a compact 108-MFMA Y-correction for their
// single boundary row, replacing the 432-MFMA serial edge_pair path.
__global__ __launch_bounds__(256, 2) void lca_iter_kernel(
        const float* __restrict__ b, float* __restrict__ u,
        const unsigned short* __restrict__ Ain,
        unsigned short* __restrict__ Aout,
        const unsigned short* __restrict__ GAh,
        const unsigned short* __restrict__ GAl,
        float* __restrict__ out, int last) {
    __shared__ __align__(1024) unsigned char smem[45056];  // 44 KB stage / 29120 ot
    unsigned short* at2h = (unsigned short*)smem;          // [rc][swizzled n]
    int blk = blockIdx.x;
    int img = blk / 14, bandq = blk % 14;
    int i0o = bandq*4;                 // first output row of the band
    int t = threadIdx.x;
    // Phase 1: padded rows R = 4*bandq .. +5 (6 rows x 58 x 64 fp16) -> LDS.
    {
        const char* gbase = (const char*)(Ain + (size_t)img*AIMG
                              + (size_t)i0o*AROW*64) + (t & 63)*16;
        char* lbase = (char*)smem;
        int w = t >> 6;
        for (int c = w; c < 44; c += 4) {
            __builtin_amdgcn_global_load_lds(
                (const __attribute__((address_space(1))) unsigned int*)(gbase + c*1024),
                (__attribute__((address_space(3))) unsigned int*)(lbase + c*1024),
                16, 0, 0);
        }
    }
    __syncthreads();
    int lane = t & 63, wave = t >> 6;
    int mhalf = wave & 1, cgrp = wave >> 1;
    int khalf = lane >> 5, cl = lane & 31;
    int pj = cgrp*32 + cl;
    int pjx = (pj < 56) ? pj : 0;                // clamp invalid columns
    floatx16 a00, a01, a10, a11;
#pragma unroll
    for (int i = 0; i < 16; ++i) { a00[i]=0.f; a01[i]=0.f; a10[i]=0.f; a11[i]=0.f; }
    const uint4* Gh4 = (const uint4*)GAh;
    const uint4* Gl4 = (const uint4*)GAl;
    const uint4* B4h = (const uint4*)at2h;
    int tbx = (cgrp == 0) ? 3 : 4;               // X boundary table
    int txoff = (tbx*9)*512;
    unsigned msel = (cl == ((cgrp == 0) ? 0 : 23)) ? 0xFFFFFFFFu : 0u;
    // ---- uniform main path: A double-buffered, B single-buffered, 12 bodies ----
    {
        uint4 Aa[9], Ab[9], B[6];
        load_a(Aa, Gh4, Gl4, txoff, 0, mhalf, lane);
#pragma unroll 1
        for (int it2 = 0; it2 < 6; ++it2) {
            int bb = it2*2;
            load_a(Ab, Gh4, Gl4, txoff, bb+1, mhalf, lane);
            load_b6(B, B4h, bb, khalf, pjx);
            do_mfma2(a00, a01, a10, a11, Aa, B, msel);
            if (it2 < 5) {
                load_a(Aa, Gh4, Gl4, txoff, bb+2, mhalf, lane);
            }
            load_b6(B, B4h, bb+1, khalf, pjx);
            do_mfma2(a00, a01, a10, a11, Ab, B, msel);
        }
    }
    // ---- Y-boundary correction (bandq 0: row 0 -> a00; bandq 13: row 55 -> a11) ----
    if (bandq == 0) {
        int tbc = (cgrp == 0) ? 5 : 6;
        edge_corr(a00, B4h, Gh4, Gl4, 0, pjx, mhalf, khalf, lane, msel, 1, tbc);
    } else if (bandq == 13) {
        int tbc = (cgrp == 0) ? 7 : 8;
        edge_corr(a11, B4h, Gh4, Gl4, 3, pjx, mhalf, khalf, lane, msel, 2, tbc);
    }
    // Epilogue: two 2-row chunks; at2h dead after first barrier.
    float* ot = (float*)smem;          // 112*65*4 = 29120 B
    const float* bp = b + (size_t)img*IMGSZ;
    float* up = u + (size_t)img*IMGSZ;          // in-place state update
#pragma unroll
    for (int ck = 0; ck < 2; ++ck) {
        __syncthreads();               // MFMA done / prev chunk reads done
        const floatx16& eA = (ck == 0) ? a00 : a10;
        const floatx16& eB = (ck == 0) ? a01 : a11;
        if (pj < 56) {
#pragma unroll
            for (int r16 = 0; r16 < 16; ++r16) {
                int row = (r16 & 3) + 8*(r16 >> 2) + 4*khalf;
                int m = mhalf*32 + row;
                ot[pj*65 + m] = eA[r16];
                ot[(56 + pj)*65 + m] = eB[r16];
            }
        }
        __syncthreads();
#pragma unroll
        for (int half = 0; half < 2; ++half) {
            // load phase: u,b for 14 passes into registers (static indices)
            float ur[14], br[14];
#pragma unroll
            for (int p = 0; p < 14; ++p) {
                int idx = (half*14 + p)*256 + t;
                int n = idx & 63;
                int rest = idx >> 6;                // 0..111
                int pi = (rest >= 56) ? 1 : 0;
                int j = rest - 56*pi;
                int g = ((i0o + ck*2 + pi)*OW + j)*64 + n;
                ur[p] = up[g];
                br[p] = bp[g];
            }
            // compute/store phase
#pragma unroll
            for (int p = 0; p < 14; ++p) {
                int idx = (half*14 + p)*256 + t;
                int n = idx & 63;
                int rest = idx >> 6;
                int pi = (rest >= 56) ? 1 : 0;
                int j = rest - 56*pi;
                int iout = i0o + ck*2 + pi;
                int g = (iout*OW + j)*64 + n;
                float uo = ur[p];
                float gram = ot[(pi*56 + j)*65 + n];
                float un = uo + ETA * (br[p] - uo - gram + softthr(uo));
                if (last) {
                    out[(((size_t)img*ATOMS + n)*OH + iout)*OW + j] = softthr(un);
                } else {
                    up[g] = un;
                    Aout[a_off(img, iout + 1, j + 1, n)] = f2h(softthr(un));
                }
            }
        }
    }
}

extern "C" void kernel_launch(void* const* d_in, const int* in_sizes, int n_in,
                              void* d_out, int out_size, void* d_ws, size_t ws_size,
                              hipStream_t stream) {
    const float* x = (const float*)d_in[0];
    const float* D = (const float*)d_in[1];
    float* out = (float*)d_out;
    float* ws = (float*)d_ws;
    float* b  = ws;                        // NLAT f32 (channel-last)
    float* u  = b  + NLAT;                 // NLAT f32 (single buffer, in-place)
    float* DT = u  + NLAT;                 // 12288 f32
    float* Gf = DT + 12288;                // 81*4096 f32
    unsigned short* GAh = (unsigned short*)(Gf + 331776);
    unsigned short* GAl = GAh + 331776;
    unsigned short* DAh = GAl + 331776;
    unsigned short* DAl = DAh + 12288;
    unsigned short* A0  = DAl + 12288;     // 64*215552 ushorts (padded stride)
    unsigned short* A1  = A0 + (size_t)BATCH*AIMG;
    prep_a_kernel<<<1878, 256, 0, stream>>>(D, A0, DT, DAh, DAl);
    prep_gram_kernel<<<1296, 256, 0, stream>>>(DT, Gf);
    prep_packg_kernel<<<162, 256, 0, stream>>>(Gf, GAh, GAl);
    conv_b_kernel<<<BATCH*49, 256, 0, stream>>>(x, DAh, DAl, b, u, A0);
    unsigned short* ain = A0; unsigned short* aout = A1;
    for (int it = 0; it < 9; ++it) {       // iterations 2..10 (iter 1 folded)
        int last = (it == 8);
        lca_iter_kernel<<<BATCH*14, 256, 0, stream>>>(b, u, ain, aout, GAh, GAl, out, last);
        unsigned short* tmp = ain; ain = aout; aout = tmp;
    }
}

// Round 15
// 887.019 us; speedup vs baseline: 12.6076x; 1.0969x over previous
//
#include <hip/hip_runtime.h>

#define BATCH 64
#define ATOMS 64
#define CIN 3
#define KS 8
#define H 224
#define W 224
#define OH 56
#define OW 56
#define NLAT (BATCH*ATOMS*OH*OW)   // 12,845,056
#define IMGSZ (OH*OW*ATOMS)        // 200,704 elems per image (channel-last)
#define LAM 0.1f
#define ETA 0.1f
// a-buffer: fp16, zero-padded halo, pre-swizzled: [img][R=0..57][C=0..57][64]
// element (R,C,n) at slot ((n>>3) ^ ((2R+C)&7))*8 + (n&7) within the 64.
// Per-image stride includes a 256-ushort (512 B) tail pad so the 44-chunk
// DMA overread of the last band stays in-bounds.
#define AROW 58
#define AIMG (AROW*AROW*64 + 256)  // 215,552 ushorts per image (padded)

typedef __attribute__((ext_vector_type(8)))  __bf16    bf16x8;
typedef __attribute__((ext_vector_type(8)))  _Float16  f16x8;
typedef __attribute__((ext_vector_type(16))) float     floatx16;

union FragU { uint4 u; bf16x8 v; };
union FragH { uint4 u; f16x8 v; };
union HalfBits { _Float16 h; unsigned short s; };

__device__ __forceinline__ float softthr(float u) {
    float p = u - LAM;  p = p > 0.f ? p : 0.f;
    float q = -u - LAM; q = q > 0.f ? q : 0.f;
    return p - q;
}
__device__ __forceinline__ unsigned short f2bf(float f) {   // RNE
    union { float f; unsigned int u; } c; c.f = f;
    unsigned int r = c.u + 0x7fffu + ((c.u >> 16) & 1u);
    return (unsigned short)(r >> 16);
}
__device__ __forceinline__ float bf2f(unsigned short h) {
    union { unsigned int u; float f; } c; c.u = ((unsigned int)h) << 16;
    return c.f;
}
__device__ __forceinline__ unsigned short f2h(float f) {    // fp16 bits, RNE
    HalfBits hb; hb.h = (_Float16)f; return hb.s;
}
__device__ __forceinline__ float h2f(unsigned short s) {
    HalfBits hb; hb.s = s; return (float)hb.h;
}
// swizzled ushort offset of atom n at padded coords (R,C) within an image
__device__ __forceinline__ size_t a_off(int img, int R, int C, int n) {
    return (size_t)img*AIMG + ((size_t)R*AROW + C)*64
         + ((((n >> 3) ^ ((2*R + C) & 7)) << 3) | (n & 7));
}

// Merged independent prep: blocks [0,1824) zero a-buffer halos,
// [1824,1872) build DT, [1872,1878) pack D (bf16 split).
__global__ void prep_a_kernel(const float* __restrict__ D,
                              unsigned short* __restrict__ A,
                              float* __restrict__ DT,
                              unsigned short* __restrict__ DAh,
                              unsigned short* __restrict__ DAl) {
    int bb = blockIdx.x;
    if (bb < 1824) {
        int idx = bb * 256 + threadIdx.x;   // 128 img-buf x 228 cells x 16 quads
        int ib = idx / 3648, r = idx % 3648;
        int cell = r >> 4, q = r & 15;
        int R, C;
        if      (cell < 58)  { R = 0;  C = cell; }
        else if (cell < 116) { R = 57; C = cell - 58; }
        else if (cell < 172) { R = cell - 116 + 1; C = 0; }
        else                 { R = cell - 172 + 1; C = 57; }
        size_t off = (size_t)ib*AIMG + ((size_t)R*AROW + C)*64 + q*4;
        *(ushort4*)(A + off) = make_ushort4(0, 0, 0, 0);
    } else if (bb < 1872) {
        int idx = (bb - 1824) * 256 + threadIdx.x;
        if (idx < CIN*KS*KS*ATOMS) {
            int m = idx & 63;
            int r = idx >> 6;
            int xk = r & 7, y = (r >> 3) & 7, c = r >> 6;
            DT[idx] = D[((m*CIN + c)*KS + y)*KS + xk];
        }
    } else {
        int g = (bb - 1872) * 256 + threadIdx.x;
        if (g >= 1536) return;
        int lane = g & 63;
        int r = g >> 6;
        int kstep = r % 12, mhalf = r / 12;
        int m = mhalf*32 + (lane & 31);
        int k0 = kstep*16 + (lane >> 5)*8;
#pragma unroll
        for (int j = 0; j < 8; ++j) {
            float v = D[m*192 + k0 + j];
            unsigned short h = f2bf(v);
            DAh[g*8 + j] = h;
            DAl[g*8 + j] = f2bf(v - bf2f(h));
        }
    }
}

// 9 table-sets (inclusion-exclusion for boundary classes), 9 dpq each.
__global__ void prep_gram_kernel(const float* __restrict__ DT,
                                 float* __restrict__ G) {
    int blk = blockIdx.x;              // td*16 + nchunk
    int td = blk >> 4;
    int tbl = td / 9, dpq = td % 9;
    int dp = dpq / 3, dq = dpq % 3;
    int di = 1 - dp, dj = 1 - dq;
    int ylo = (0 > -4*di) ? 0 : -4*di;
    int yhi = (8 < 8-4*di) ? 8 : 8-4*di;
    int xlo = (0 > -4*dj) ? 0 : -4*dj;
    int xhi = (8 < 8-4*dj) ? 8 : 8-4*dj;
    if (tbl==1 || tbl==5 || tbl==6) { if (yhi > 2) yhi = 2; }
    if (tbl==2 || tbl==7 || tbl==8) { if (ylo < 6) ylo = 6; }
    if (tbl==3 || tbl==5 || tbl==7) { if (xhi > 2) xhi = 2; }
    if (tbl==4 || tbl==6 || tbl==8) { if (xlo < 6) xlo = 6; }
    float sign = (tbl >= 1 && tbl <= 4) ? -1.f : 1.f;
    int t = threadIdx.x;
    int m = t & 63;
    int n = (blk & 15)*4 + (t >> 6);
    float s = 0.f;
    for (int c = 0; c < CIN; ++c)
        for (int y = ylo; y < yhi; ++y)
            for (int x = xlo; x < xhi; ++x)
                s += DT[((c*8+y)*8+x)*64 + m] *
                     DT[((c*8+y+4*di)*8 + (x+4*dj))*64 + n];
    G[td*4096 + n*64 + m] = sign * s;
}

// Pack G into MFMA A-operand layout, split FP16 hi/lo.
__global__ void prep_packg_kernel(const float* __restrict__ G,
                                  unsigned short* __restrict__ GAh,
                                  unsigned short* __restrict__ GAl) {
    int g = blockIdx.x * 256 + threadIdx.x;      // 162*256 = 41472 groups
    int lane = g & 63;
    int r = g >> 6;
    int kstep = r & 3; r >>= 2;
    int mhalf = r & 1; int td = r >> 1;          // tbl*9+dpq
    int m = mhalf*32 + (lane & 31);
    int n = kstep*16 + (lane >> 5)*8;
    const float* src = G + td*4096 + n*64 + m;
#pragma unroll
    for (int j = 0; j < 8; ++j) {
        float v = src[j*64];
        unsigned short h = f2h(v);
        GAh[g*8 + j] = h;
        GAl[g*8 + j] = f2h(v - h2f(h));
    }
}

// b = conv2d(x, D, stride4, pad2); u = 0.1*b; a1 = softthr(u) -> A0 (swizzled).
// Output CHANNEL-LAST [i][j][n].
__global__ __launch_bounds__(256) void conv_b_kernel(
        const float* __restrict__ x,
        const unsigned short* __restrict__ DAh,
        const unsigned short* __restrict__ DAl,
        float* __restrict__ b, float* __restrict__ u,
        unsigned short* __restrict__ A0) {
    __shared__ __align__(16) unsigned short xth[CIN*36*36];
    __shared__ __align__(16) unsigned short xtl[CIN*36*36];
    __shared__ float ot[64*65];
    int blk = blockIdx.x;
    int img = blk / 49, tile = blk % 49;
    int i0 = (tile / 7) * 8, j0 = (tile % 7) * 8;
    int t = threadIdx.x;
    int r0 = 4*i0 - 2, c0 = 4*j0 - 2;
    for (int f = t; f < CIN*36*36; f += 256) {
        int cc = f / 1296, rem = f % 1296;
        int rr = rem / 36, qq = rem % 36;
        int Y = r0 + rr, X = c0 + qq;
        float v = 0.f;
        if (Y >= 0 && Y < H && X >= 0 && X < W)
            v = x[((img*CIN + cc)*H + Y)*W + X];
        unsigned short h = f2bf(v);
        xth[f] = h;
        xtl[f] = f2bf(v - bf2f(h));
    }
    __syncthreads();
    int lane = t & 63, wave = t >> 6;
    int mhalf = wave & 1, poshalf = wave >> 1;
    int pos = poshalf*32 + (lane & 31), pi = pos >> 3, pj = pos & 7;
    int khalf = lane >> 5;
    floatx16 acc;
#pragma unroll
    for (int i = 0; i < 16; ++i) acc[i] = 0.f;
    const uint4* Ah4 = (const uint4*)DAh;
    const uint4* Al4 = (const uint4*)DAl;
#pragma unroll 3
    for (int kstep = 0; kstep < 12; ++kstep) {
        int k0 = kstep*16 + khalf*8;
        int cc = k0 >> 6, yy = (k0 >> 3) & 7;
        int boff = cc*1296 + (4*pi + yy)*36 + 4*pj;
        FragU ah, al, bh, bl;
        ah.u = Ah4[(mhalf*12 + kstep)*64 + lane];
        al.u = Al4[(mhalf*12 + kstep)*64 + lane];
        const uint2* ph = (const uint2*)(xth + boff);
        uint2 h0 = ph[0], h1 = ph[1];
        bh.u = make_uint4(h0.x, h0.y, h1.x, h1.y);
        const uint2* pl = (const uint2*)(xtl + boff);
        uint2 l0 = pl[0], l1 = pl[1];
        bl.u = make_uint4(l0.x, l0.y, l1.x, l1.y);
        acc = __builtin_amdgcn_mfma_f32_32x32x16_bf16(ah.v, bh.v, acc, 0, 0, 0);
        acc = __builtin_amdgcn_mfma_f32_32x32x16_bf16(ah.v, bl.v, acc, 0, 0, 0);
        acc = __builtin_amdgcn_mfma_f32_32x32x16_bf16(al.v, bh.v, acc, 0, 0, 0);
    }
#pragma unroll
    for (int r16 = 0; r16 < 16; ++r16) {
        int row = (r16 & 3) + 8*(r16 >> 2) + 4*khalf;
        ot[(mhalf*32 + row)*65 + pos] = acc[r16];
    }
    __syncthreads();
    // channel-last epilogue: lane = channel -> 256B contiguous stores
    int m = t & 63;
    float* bp = b + (size_t)img*IMGSZ;
    float* up = u + (size_t)img*IMGSZ;
#pragma unroll
    for (int e = 0; e < 16; ++e) {
        int pp = e*4 + (t >> 6);
        int gi = i0 + (pp >> 3), gj = j0 + (pp & 7);
        int gidx = (gi*OW + gj)*64 + m;
        float v = ot[m*65 + pp];
        bp[gidx] = v;
        float uv = ETA * v;
        up[gidx] = uv;
        A0[a_off(img, gi + 1, gj + 1, m)] = f2h(softthr(uv));
    }
}

// ---- MFMA helpers ----
__device__ __forceinline__ void load_a(uint4 (&A)[9], const uint4* __restrict__ Gh4,
                                       const uint4* __restrict__ Gl4,
                                       int txoff, int bb, int mhalf, int lane) {
    int dq = bb >> 2, ks = bb & 3;
#pragma unroll
    for (int dp = 0; dp < 3; ++dp) {
        int abase = (((3*dp + dq)*2 + mhalf)*4 + ks)*64 + lane;
        A[dp*3+0] = Gh4[abase];
        A[dp*3+1] = Gl4[abase];
        A[dp*3+2] = Gh4[txoff + abase];
    }
}
// 6 B-fragment slots (rows i0o..i0o+5 of the staged band) for one body.
__device__ __forceinline__ void load_b6(uint4 (&B)[6], const uint4* __restrict__ B4h,
                                        int bb, int khalf, int pjx) {
    int dq = bb >> 2, ks = bb & 3;
    int kg2 = ks*2 + khalf;
#pragma unroll
    for (int p = 0; p < 6; ++p) {
        int rc = p*58 + pjx + dq;
        B[p] = B4h[rc*8 + (kg2 ^ (rc & 7))];
    }
}
// Two row-pairs sharing the same A fragments: pair0 = rows (i0o, i0o+1)
// using slots dp, dp+1; pair1 = rows (i0o+2, i0o+3) using slots dp+2, dp+3.
__device__ __forceinline__ void do_mfma2(floatx16& a00, floatx16& a01,
                                         floatx16& a10, floatx16& a11,
                                         const uint4 (&A)[9], const uint4 (&B)[6],
                                         unsigned msel) {
    __builtin_amdgcn_s_setprio(1);
#pragma unroll
    for (int dp = 0; dp < 3; ++dp) {
        FragH a0, a1, ax;
        a0.u = A[dp*3+0]; a1.u = A[dp*3+1]; ax.u = A[dp*3+2];
        FragH b0, b1, bm0, bm1;
        b0.u = B[dp]; b1.u = B[dp+1];
        bm0.u = make_uint4(b0.u.x & msel, b0.u.y & msel,
                           b0.u.z & msel, b0.u.w & msel);
        bm1.u = make_uint4(b1.u.x & msel, b1.u.y & msel,
                           b1.u.z & msel, b1.u.w & msel);
        a00 = __builtin_amdgcn_mfma_f32_32x32x16_f16(a0.v, b0.v, a00, 0,0,0);
        a01 = __builtin_amdgcn_mfma_f32_32x32x16_f16(a0.v, b1.v, a01, 0,0,0);
        a00 = __builtin_amdgcn_mfma_f32_32x32x16_f16(a1.v, b0.v, a00, 0,0,0);
        a01 = __builtin_amdgcn_mfma_f32_32x32x16_f16(a1.v, b1.v, a01, 0,0,0);
        a00 = __builtin_amdgcn_mfma_f32_32x32x16_f16(ax.v, bm0.v, a00, 0,0,0);
        a01 = __builtin_amdgcn_mfma_f32_32x32x16_f16(ax.v, bm1.v, a01, 0,0,0);
        FragH c0, c1, cm0, cm1;
        c0.u = B[dp+2]; c1.u = B[dp+3];
        cm0.u = make_uint4(c0.u.x & msel, c0.u.y & msel,
                           c0.u.z & msel, c0.u.w & msel);
        cm1.u = make_uint4(c1.u.x & msel, c1.u.y & msel,
                           c1.u.z & msel, c1.u.w & msel);
        a10 = __builtin_amdgcn_mfma_f32_32x32x16_f16(a0.v, c0.v, a10, 0,0,0);
        a11 = __builtin_amdgcn_mfma_f32_32x32x16_f16(a0.v, c1.v, a11, 0,0,0);
        a10 = __builtin_amdgcn_mfma_f32_32x32x16_f16(a1.v, c0.v, a10, 0,0,0);
        a11 = __builtin_amdgcn_mfma_f32_32x32x16_f16(a1.v, c1.v, a11, 0,0,0);
        a10 = __builtin_amdgcn_mfma_f32_32x32x16_f16(ax.v, cm0.v, a10, 0,0,0);
        a11 = __builtin_amdgcn_mfma_f32_32x32x16_f16(ax.v, cm1.v, a11, 0,0,0);
    }
    __builtin_amdgcn_s_setprio(0);
}
// Y-boundary correction for ONE output row (the image-edge row): applies
// tby (hi+lo) and tbc (masked) terms on top of the interior result.
// Valid because staged halo rows are zero, so the interior path's T0/tbx
// application over them contributes nothing.
__device__ __forceinline__ void edge_corr(floatx16& tgt,
        const uint4* __restrict__ B4h, const uint4* __restrict__ Gh4,
        const uint4* __restrict__ Gl4, int slotbase, int pjx,
        int mhalf, int khalf, int lane, unsigned msel, int tby, int tbc) {
#pragma unroll 1
    for (int dq = 0; dq < 3; ++dq) {
#pragma unroll 1
        for (int ks = 0; ks < 4; ++ks) {
            int kg2 = ks*2 + khalf;
#pragma unroll
            for (int dp = 0; dp < 3; ++dp) {
                int rc = (slotbase + dp)*58 + pjx + dq;
                FragH B0, bm, ah, al, ac;
                B0.u = B4h[rc*8 + (kg2 ^ (rc & 7))];
                int ab = (((tby*9 + 3*dp + dq)*2 + mhalf)*4 + ks)*64 + lane;
                int cb = (((tbc*9 + 3*dp + dq)*2 + mhalf)*4 + ks)*64 + lane;
                ah.u = Gh4[ab];
                al.u = Gl4[ab];
                ac.u = Gh4[cb];
                bm.u = make_uint4(B0.u.x & msel, B0.u.y & msel,
                                  B0.u.z & msel, B0.u.w & msel);
                tgt = __builtin_amdgcn_mfma_f32_32x32x16_f16(ah.v, B0.v, tgt, 0,0,0);
                tgt = __builtin_amdgcn_mfma_f32_32x32x16_f16(al.v, B0.v, tgt, 0,0,0);
                tgt = __builtin_amdgcn_mfma_f32_32x32x16_f16(ac.v, bm.v, tgt, 0,0,0);
            }
        }
    }
}

// One LCA step on a 4-row x 56-col band, 256 threads = 4 waves {mhalf, cgrp}.
// R17 = R16 + float4/ushort4-vectorized epilogue: each thread handles 4
// consecutive channels (one swizzle group) -> u/b reads and u/a writes are
// 16B/8B ops; epilogue pass count 56 -> 14 (G13: hipcc never auto-vectorizes).
__global__ __launch_bounds__(256, 2) void lca_iter_kernel(
        const float* __restrict__ b, float* __restrict__ u,
        const unsigned short* __restrict__ Ain,
        unsigned short* __restrict__ Aout,
        const unsigned short* __restrict__ GAh,
        const unsigned short* __restrict__ GAl,
        float* __restrict__ out, int last) {
    __shared__ __align__(1024) unsigned char smem[45056];  // 44 KB stage / 29120 ot
    unsigned short* at2h = (unsigned short*)smem;          // [rc][swizzled n]
    int blk = blockIdx.x;
    int img = blk / 14, bandq = blk % 14;
    int i0o = bandq*4;                 // first output row of the band
    int t = threadIdx.x;
    // Phase 1: padded rows R = 4*bandq .. +5 (6 rows x 58 x 64 fp16) -> LDS.
    {
        const char* gbase = (const char*)(Ain + (size_t)img*AIMG
                              + (size_t)i0o*AROW*64) + (t & 63)*16;
        char* lbase = (char*)smem;
        int w = t >> 6;
        for (int c = w; c < 44; c += 4) {
            __builtin_amdgcn_global_load_lds(
                (const __attribute__((address_space(1))) unsigned int*)(gbase + c*1024),
                (__attribute__((address_space(3))) unsigned int*)(lbase + c*1024),
                16, 0, 0);
        }
    }
    __syncthreads();
    int lane = t & 63, wave = t >> 6;
    int mhalf = wave & 1, cgrp = wave >> 1;
    int khalf = lane >> 5, cl = lane & 31;
    int pj = cgrp*32 + cl;
    int pjx = (pj < 56) ? pj : 0;                // clamp invalid columns
    floatx16 a00, a01, a10, a11;
#pragma unroll
    for (int i = 0; i < 16; ++i) { a00[i]=0.f; a01[i]=0.f; a10[i]=0.f; a11[i]=0.f; }
    const uint4* Gh4 = (const uint4*)GAh;
    const uint4* Gl4 = (const uint4*)GAl;
    const uint4* B4h = (const uint4*)at2h;
    int tbx = (cgrp == 0) ? 3 : 4;               // X boundary table
    int txoff = (tbx*9)*512;
    unsigned msel = (cl == ((cgrp == 0) ? 0 : 23)) ? 0xFFFFFFFFu : 0u;
    // ---- uniform main path: A double-buffered, B single-buffered, 12 bodies ----
    {
        uint4 Aa[9], Ab[9], B[6];
        load_a(Aa, Gh4, Gl4, txoff, 0, mhalf, lane);
#pragma unroll 1
        for (int it2 = 0; it2 < 6; ++it2) {
            int bb = it2*2;
            load_a(Ab, Gh4, Gl4, txoff, bb+1, mhalf, lane);
            load_b6(B, B4h, bb, khalf, pjx);
            do_mfma2(a00, a01, a10, a11, Aa, B, msel);
            if (it2 < 5) {
                load_a(Aa, Gh4, Gl4, txoff, bb+2, mhalf, lane);
            }
            load_b6(B, B4h, bb+1, khalf, pjx);
            do_mfma2(a00, a01, a10, a11, Ab, B, msel);
        }
    }
    // ---- Y-boundary correction (bandq 0: row 0 -> a00; bandq 13: row 55 -> a11) ----
    if (bandq == 0) {
        int tbc = (cgrp == 0) ? 5 : 6;
        edge_corr(a00, B4h, Gh4, Gl4, 0, pjx, mhalf, khalf, lane, msel, 1, tbc);
    } else if (bandq == 13) {
        int tbc = (cgrp == 0) ? 7 : 8;
        edge_corr(a11, B4h, Gh4, Gl4, 3, pjx, mhalf, khalf, lane, msel, 2, tbc);
    }
    // Epilogue: two 2-row chunks; at2h dead after first barrier.
    float* ot = (float*)smem;          // 112*65*4 = 29120 B
    const float* bp = b + (size_t)img*IMGSZ;
    float* up = u + (size_t)img*IMGSZ;          // in-place state update
#pragma unroll
    for (int ck = 0; ck < 2; ++ck) {
        __syncthreads();               // MFMA done / prev chunk reads done
        const floatx16& eA = (ck == 0) ? a00 : a10;
        const floatx16& eB = (ck == 0) ? a01 : a11;
        if (pj < 56) {
#pragma unroll
            for (int r16 = 0; r16 < 16; ++r16) {
                int row = (r16 & 3) + 8*(r16 >> 2) + 4*khalf;
                int m = mhalf*32 + row;
                ot[pj*65 + m] = eA[r16];
                ot[(56 + pj)*65 + m] = eB[r16];
            }
        }
        __syncthreads();
        // float4 load phase: 7 quad-passes cover 2x56x64 elems (static idx)
        float4 ur4[7], br4[7];
#pragma unroll
        for (int p = 0; p < 7; ++p) {
            int qi = p*256 + t;                 // 0..1791
            int n0 = (qi & 15) * 4;
            int rest = qi >> 4;                 // 0..111
            int pi = (rest >= 56) ? 1 : 0;
            int j = rest - 56*pi;
            int g = ((i0o + ck*2 + pi)*OW + j)*64 + n0;
            ur4[p] = *(const float4*)(up + g);
            br4[p] = *(const float4*)(bp + g);
        }
        // compute/store phase (float4 u-write, ushort4 a-write)
#pragma unroll
        for (int p = 0; p < 7; ++p) {
            int qi = p*256 + t;
            int n0 = (qi & 15) * 4;
            int rest = qi >> 4;
            int pi = (rest >= 56) ? 1 : 0;
            int j = rest - 56*pi;
            int iout = i0o + ck*2 + pi;
            int g = (iout*OW + j)*64 + n0;
            float4 uv = ur4[p], bv = br4[p];
            const float* otr = ot + (pi*56 + j)*65 + n0;
            float u0 = uv.x + ETA*(bv.x - uv.x - otr[0] + softthr(uv.x));
            float u1 = uv.y + ETA*(bv.y - uv.y - otr[1] + softthr(uv.y));
            float u2 = uv.z + ETA*(bv.z - uv.z - otr[2] + softthr(uv.z));
            float u3 = uv.w + ETA*(bv.w - uv.w - otr[3] + softthr(uv.w));
            if (last) {
                size_t base = (((size_t)img*ATOMS + n0)*OH + iout)*OW + j;
                out[base]           = softthr(u0);
                out[base + OH*OW]   = softthr(u1);
                out[base + 2*OH*OW] = softthr(u2);
                out[base + 3*OH*OW] = softthr(u3);
            } else {
                *(float4*)(up + g) = make_float4(u0, u1, u2, u3);
                int R = iout + 1, C = j + 1;
                int key = (2*R + C) & 7;
                unsigned short* cell = Aout + (size_t)img*AIMG
                                     + ((size_t)R*AROW + C)*64;
                *(ushort4*)(cell + (((n0 >> 3) ^ key) << 3) + (n0 & 7)) =
                    make_ushort4(f2h(softthr(u0)), f2h(softthr(u1)),
                                 f2h(softthr(u2)), f2h(softthr(u3)));
            }
        }
    }
}

extern "C" void kernel_launch(void* const* d_in, const int* in_sizes, int n_in,
                              void* d_out, int out_size, void* d_ws, size_t ws_size,
                              hipStream_t stream) {
    const float* x = (const float*)d_in[0];
    const float* D = (const float*)d_in[1];
    float* out = (float*)d_out;
    float* ws = (float*)d_ws;
    float* b  = ws;                        // NLAT f32 (channel-last)
    float* u  = b  + NLAT;                 // NLAT f32 (single buffer, in-place)
    float* DT = u  + NLAT;                 // 12288 f32
    float* Gf = DT + 12288;                // 81*4096 f32
    unsigned short* GAh = (unsigned short*)(Gf + 331776);
    unsigned short* GAl = GAh + 331776;
    unsigned short* DAh = GAl + 331776;
    unsigned short* DAl = DAh + 12288;
    unsigned short* A0  = DAl + 12288;     // 64*215552 ushorts (padded stride)
    unsigned short* A1  = A0 + (size_t)BATCH*AIMG;
    prep_a_kernel<<<1878, 256, 0, stream>>>(D, A0, DT, DAh, DAl);
    prep_gram_kernel<<<1296, 256, 0, stream>>>(DT, Gf);
    prep_packg_kernel<<<162, 256, 0, stream>>>(Gf, GAh, GAl);
    conv_b_kernel<<<BATCH*49, 256, 0, stream>>>(x, DAh, DAl, b, u, A0);
    unsigned short* ain = A0; unsigned short* aout = A1;
    for (int it = 0; it < 9; ++it) {       // iterations 2..10 (iter 1 folded)
        int last = (it == 8);
        lca_iter_kernel<<<BATCH*14, 256, 0, stream>>>(b, u, ain, aout, GAh, GAl, out, last);
        unsigned short* tmp = ain; ain = aout; aout = tmp;
    }
}